// Round 1
// 2902.487 us; speedup vs baseline: 2.3800x; 2.3800x over previous
//
#include <hip/hip_runtime.h>
#include <math.h>

#define NB 32
#define NT 512
#define NDIN 1024
#define NDCB 256
#define NKCB 8192
#define NHMID 512
#define NROWS (NB*NT)   // 16384

typedef _Float16 half2_t __attribute__((ext_vector_type(2)));

#if __has_builtin(__builtin_amdgcn_fdot2)
__device__ __forceinline__ float dot2f(half2_t a, half2_t b, float c) {
    return __builtin_amdgcn_fdot2(a, b, c, false);
}
#else
__device__ __forceinline__ float dot2f(half2_t a, half2_t b, float c) {
    return fmaf((float)a[0], (float)b[0], fmaf((float)a[1], (float)b[1], c));
}
#endif

// ---------------- fp64-accumulate tiled GEMM: C = act(A(MxK) * B(NxK)^T + bias) ----------------
// fp32 in/out, fp64 accumulation: output = fl(exact), the canonical fp32 result.  [LOCKED numerics]
template<bool RELU>
__global__ __launch_bounds__(256) void gemm_nt_f64_kernel(
    const float* __restrict__ A, const float* __restrict__ Bm,
    const float* __restrict__ bias, float* __restrict__ C,
    int M, int N, int K)
{
    __shared__ double a_s[16*64];
    __shared__ double b_s[16*64];
    const int tid = threadIdx.x;
    const int bn0 = blockIdx.x * 64;
    const int bm0 = blockIdx.y * 64;
    const int lr = tid >> 2;          // 0..63
    const int kq = (tid & 3) << 2;    // 0,4,8,12
    const int tx = tid & 15, ty = tid >> 4;
    double acc[4][4] = {};
    const float* Ap = A + (size_t)(bm0 + lr) * K + kq;
    const float* Bp = Bm + (size_t)(bn0 + lr) * K + kq;
    for (int kt = 0; kt < K; kt += 16) {
        float4 a = *(const float4*)(Ap + kt);
        float4 b = *(const float4*)(Bp + kt);
        __syncthreads();
        a_s[(kq+0)*64+lr] = (double)a.x; a_s[(kq+1)*64+lr] = (double)a.y;
        a_s[(kq+2)*64+lr] = (double)a.z; a_s[(kq+3)*64+lr] = (double)a.w;
        b_s[(kq+0)*64+lr] = (double)b.x; b_s[(kq+1)*64+lr] = (double)b.y;
        b_s[(kq+2)*64+lr] = (double)b.z; b_s[(kq+3)*64+lr] = (double)b.w;
        __syncthreads();
        #pragma unroll
        for (int kk = 0; kk < 16; kk++) {
            double aa[4], bb[4];
            #pragma unroll
            for (int u = 0; u < 4; u++) { aa[u] = a_s[kk*64 + ty*4 + u]; bb[u] = b_s[kk*64 + tx*4 + u]; }
            #pragma unroll
            for (int i = 0; i < 4; i++)
                #pragma unroll
                for (int j = 0; j < 4; j++)
                    acc[i][j] = fma(aa[i], bb[j], acc[i][j]);
        }
    }
    const float4 b4 = *(const float4*)&bias[bn0 + tx*4];
    const double bc[4] = {(double)b4.x, (double)b4.y, (double)b4.z, (double)b4.w};
    #pragma unroll
    for (int i = 0; i < 4; i++) {
        float o[4];
        #pragma unroll
        for (int j = 0; j < 4; j++) {
            double v = acc[i][j] + bc[j];
            if (RELU) v = fmax(v, 0.0);
            o[j] = (float)v;
        }
        *(float4*)&C[(size_t)(bm0 + ty*4 + i)*N + bn0 + tx*4] =
            make_float4(o[0], o[1], o[2], o[3]);
    }
}

// ---------------- conv1d k=3 SAME, fp64 accumulation ----------------  [LOCKED numerics]
__global__ __launch_bounds__(256) void conv3_f64_kernel(
    const float* __restrict__ H2, const float* __restrict__ W3,
    const float* __restrict__ bias, float* __restrict__ F)
{
    __shared__ double a_s[16*68];       // [k][local row], local l <-> global bm0-1+l
    __shared__ double b_s[3][16*64];
    const int tid = threadIdx.x;
    const int bn0 = blockIdx.x * 64;
    const int bm0 = blockIdx.y * 64;
    const int lr = tid >> 2;
    const int kq = (tid & 3) << 2;
    const int tx = tid & 15, ty = tid >> 4;
    const int tmod = bm0 & (NT-1);
    const bool has_top = (tmod != 0);
    const bool has_bot = (tmod + 64 < NT);
    double acc[4][4] = {};
    for (int kt = 0; kt < NDCB; kt += 16) {
        float4 a = make_float4(0.f,0.f,0.f,0.f);
        if (lr >= 1 || has_top)
            a = *(const float4*)&H2[(size_t)(bm0 - 1 + lr)*NDCB + kt + kq];
        float4 e = make_float4(0.f,0.f,0.f,0.f);
        int l2 = 0, kq2 = 0;
        if (tid < 8) {
            l2 = 64 + (tid >> 2); kq2 = (tid & 3) << 2;
            if (l2 == 64 || has_bot)
                e = *(const float4*)&H2[(size_t)(bm0 - 1 + l2)*NDCB + kt + kq2];
        }
        float4 w[3];
        #pragma unroll
        for (int s = 0; s < 3; s++)
            w[s] = *(const float4*)&W3[(size_t)s*65536 + (size_t)(bn0 + lr)*NDCB + kt + kq];
        __syncthreads();
        a_s[(kq+0)*68+lr]=(double)a.x; a_s[(kq+1)*68+lr]=(double)a.y;
        a_s[(kq+2)*68+lr]=(double)a.z; a_s[(kq+3)*68+lr]=(double)a.w;
        if (tid < 8) {
            a_s[(kq2+0)*68+l2]=(double)e.x; a_s[(kq2+1)*68+l2]=(double)e.y;
            a_s[(kq2+2)*68+l2]=(double)e.z; a_s[(kq2+3)*68+l2]=(double)e.w;
        }
        #pragma unroll
        for (int s = 0; s < 3; s++) {
            b_s[s][(kq+0)*64+lr]=(double)w[s].x; b_s[s][(kq+1)*64+lr]=(double)w[s].y;
            b_s[s][(kq+2)*64+lr]=(double)w[s].z; b_s[s][(kq+3)*64+lr]=(double)w[s].w;
        }
        __syncthreads();
        #pragma unroll
        for (int kk = 0; kk < 16; kk++) {
            double aa[6];
            #pragma unroll
            for (int u = 0; u < 6; u++) aa[u] = a_s[kk*68 + ty*4 + u];
            #pragma unroll
            for (int s = 0; s < 3; s++) {
                double bb[4];
                #pragma unroll
                for (int u = 0; u < 4; u++) bb[u] = b_s[s][kk*64 + tx*4 + u];
                #pragma unroll
                for (int i = 0; i < 4; i++)
                    #pragma unroll
                    for (int j = 0; j < 4; j++)
                        acc[i][j] = fma(aa[i+s], bb[j], acc[i][j]);
            }
        }
    }
    const float4 b4 = *(const float4*)&bias[bn0 + tx*4];
    const double bc[4] = {(double)b4.x, (double)b4.y, (double)b4.z, (double)b4.w};
    #pragma unroll
    for (int i = 0; i < 4; i++) {
        const size_t base = (size_t)(bm0 + ty*4 + i)*NDCB + bn0 + tx*4;
        *(float4*)&F[base] = make_float4((float)(acc[i][0]+bc[0]), (float)(acc[i][1]+bc[1]),
                                         (float)(acc[i][2]+bc[2]), (float)(acc[i][3]+bc[3]));
    }
}

// ---------------- VQ: fp32 GEMM prefilter + canonical-fp32-quantized argmin on near-ties ----
// [LOCKED numerics] d2 = fl32( fl32( s_f - 2*G ) + s_c ), argmin with first-index tie-break.
__global__ __launch_bounds__(512) void vq_kernel(
    const float* __restrict__ F, const float* __restrict__ CB,
    const float* __restrict__ cnorm, float* __restrict__ idx_out,
    float* __restrict__ qout, float* __restrict__ msd_acc)
{
    __shared__ float a_s[32*64];     // [k][row]   8 KB
    __shared__ float b_s[32*128];    // [k][col]  16 KB
    __shared__ float red_v[64*64];   // top-2 per (row, tx); reused for msd reduce
    __shared__ int   red_i[64*64];
    __shared__ int   bests[64];
    __shared__ int   cand[64][12];
    __shared__ int   ccnt[64];
    const int tid = threadIdx.x;
    const int m0 = blockIdx.x * 64;
    const int tx = tid & 31, ty = tid >> 5;   // 32 x 16
    float mv1[4], mv2[4]; int mi1[4], mi2[4];
    #pragma unroll
    for (int i = 0; i < 4; i++) { mv1[i]=3.0e38f; mv2[i]=3.0e38f; mi1[i]=0x7fffffff; mi2[i]=0x7fffffff; }
    const int ar  = tid >> 3;            // 0..63
    const int akq = (tid & 7) << 2;      // 0..28
    for (int n0 = 0; n0 < NKCB; n0 += 128) {
        float dot[4][4] = {};
        for (int kt = 0; kt < NDCB; kt += 32) {
            __syncthreads();
            {
                float4 a = *(const float4*)&F[(size_t)(m0 + ar)*NDCB + kt + akq];
                a_s[(akq+0)*64+ar]=a.x; a_s[(akq+1)*64+ar]=a.y;
                a_s[(akq+2)*64+ar]=a.z; a_s[(akq+3)*64+ar]=a.w;
            }
            #pragma unroll
            for (int u = 0; u < 2; u++) {
                int e2 = tid + u*512;
                int c = e2 >> 3, kqb = (e2 & 7) << 2;
                float4 b = *(const float4*)&CB[(size_t)(n0 + c)*NDCB + kt + kqb];
                b_s[(kqb+0)*128+c]=b.x; b_s[(kqb+1)*128+c]=b.y;
                b_s[(kqb+2)*128+c]=b.z; b_s[(kqb+3)*128+c]=b.w;
            }
            __syncthreads();
            #pragma unroll
            for (int kk = 0; kk < 32; kk++) {
                const float4 av = *(const float4*)&a_s[kk*64 + ty*4];
                const float4 bv = *(const float4*)&b_s[kk*128 + tx*4];
                const float aa[4]={av.x,av.y,av.z,av.w};
                const float bb[4]={bv.x,bv.y,bv.z,bv.w};
                #pragma unroll
                for (int i=0;i<4;i++)
                    #pragma unroll
                    for (int j=0;j<4;j++)
                        dot[i][j] = fmaf(aa[i], bb[j], dot[i][j]);
            }
        }
        #pragma unroll
        for (int j = 0; j < 4; j++) {
            const int col = n0 + tx*4 + j;
            const float cn = cnorm[col];
            #pragma unroll
            for (int i = 0; i < 4; i++) {
                float s = fmaf(-2.0f, dot[i][j], cn);
                if (s < mv1[i]) { mv2[i]=mv1[i]; mi2[i]=mi1[i]; mv1[i]=s; mi1[i]=col; }
                else if (s < mv2[i]) { mv2[i]=s; mi2[i]=col; }
            }
        }
    }
    #pragma unroll
    for (int i = 0; i < 4; i++) {
        const int row = ty*4 + i;
        red_v[row*64 + tx*2 + 0] = mv1[i]; red_i[row*64 + tx*2 + 0] = mi1[i];
        red_v[row*64 + tx*2 + 1] = mv2[i]; red_i[row*64 + tx*2 + 1] = mi2[i];
    }
    __syncthreads();
    if (tid < 64) {
        float bv = 3.0e38f; int bi = 0x7fffffff;
        for (int e = 0; e < 64; e++) {
            float v = red_v[tid*64 + e]; int ii = red_i[tid*64 + e];
            if (v < bv || (v == bv && ii < bi)) { bv = v; bi = ii; }
        }
        int cnt = 0;
        for (int e = 0; e < 64; e++) {
            if (red_v[tid*64 + e] < bv + 1.0e-6f) {
                if (cnt < 12) cand[tid][cnt] = red_i[tid*64 + e];
                cnt++;
            }
        }
        bests[tid] = bi;
        ccnt[tid] = (cnt > 12) ? 12 : cnt;
    }
    __syncthreads();
    // Canonical fp32-quantized rescore of near-tie rows (one wave per row, round-robin).
    {
        const int wid = tid >> 6, lane = tid & 63;
        for (int r = wid; r < 64; r += 8) {
            const int nc = ccnt[r];
            if (nc < 2) continue;
            double sf = 0.0;
            #pragma unroll
            for (int u = 0; u < 4; u++) {
                double fv = (double)F[(size_t)(m0+r)*NDCB + lane*4 + u];
                sf = fma(fv, fv, sf);
            }
            #pragma unroll
            for (int off = 32; off > 0; off >>= 1) sf += __shfl_down(sf, off);
            const float sf32 = (float)sf;          // valid on lane 0
            float bd2 = 0.0f; int bidx = 0x7fffffff;
            for (int c = 0; c < nc; c++) {
                const int k = cand[r][c];
                double g = 0.0;
                #pragma unroll
                for (int u = 0; u < 4; u++) {
                    double cv = (double)CB[(size_t)k*NDCB + lane*4 + u];
                    double fv = (double)F[(size_t)(m0+r)*NDCB + lane*4 + u];
                    g = fma(cv, fv, g);
                }
                #pragma unroll
                for (int off = 32; off > 0; off >>= 1) g += __shfl_down(g, off);
                if (lane == 0) {
                    const float G32 = (float)g;
                    const float t  = sf32 - 2.0f*G32;
                    const float d2 = t + cnorm[k];
                    if (c == 0 || d2 < bd2 || (d2 == bd2 && k < bidx)) { bd2 = d2; bidx = k; }
                }
            }
            if (lane == 0) bests[r] = bidx;
        }
    }
    __syncthreads();
    if (tid < 64) idx_out[m0 + tid] = (float)bests[tid];
    float lsum = 0.0f;
    #pragma unroll
    for (int s = 0; s < 8; s++) {
        int e = tid + s*512;
        int row = e >> 6, kqe = (e & 63) << 2;
        float4 q = *(const float4*)&CB[(size_t)bests[row]*NDCB + kqe];
        float4 f = *(const float4*)&F[(size_t)(m0+row)*NDCB + kqe];
        float dx=f.x-q.x, dy=f.y-q.y, dz=f.z-q.z, dw=f.w-q.w;
        lsum += dx*dx + dy*dy + dz*dz + dw*dw;
        *(float4*)&qout[(size_t)(m0+row)*NDCB + kqe] = q;
    }
    red_v[tid] = lsum;
    __syncthreads();
    for (int off = 256; off > 0; off >>= 1) {
        if (tid < off) red_v[tid] += red_v[tid + off];
        __syncthreads();
    }
    if (tid == 0) atomicAdd(msd_acc, red_v[0]);
}

// ---------------- fp32 tiled GEMM for xproj (feeds GRU/context_loss, 2% threshold) ------------
__global__ __launch_bounds__(256) void gemm_nt_kernel(
    const float* __restrict__ A, const float* __restrict__ Bm,
    const float* __restrict__ bias, float* __restrict__ C,
    int M, int N, int K)
{
    __shared__ float a_s[16*64];
    __shared__ float b_s[16*64];
    const int tid = threadIdx.x;
    const int bn0 = blockIdx.x * 64;
    const int bm0 = blockIdx.y * 64;
    const int lr = tid >> 2;
    const int kq = (tid & 3) << 2;
    const int tx = tid & 15, ty = tid >> 4;
    float acc[4][4] = {};
    const float* Ap = A + (size_t)(bm0 + lr) * K + kq;
    const float* Bp = Bm + (size_t)(bn0 + lr) * K + kq;
    for (int kt = 0; kt < K; kt += 16) {
        float4 a = *(const float4*)(Ap + kt);
        float4 b = *(const float4*)(Bp + kt);
        __syncthreads();
        a_s[(kq+0)*64+lr] = a.x; a_s[(kq+1)*64+lr] = a.y;
        a_s[(kq+2)*64+lr] = a.z; a_s[(kq+3)*64+lr] = a.w;
        b_s[(kq+0)*64+lr] = b.x; b_s[(kq+1)*64+lr] = b.y;
        b_s[(kq+2)*64+lr] = b.z; b_s[(kq+3)*64+lr] = b.w;
        __syncthreads();
        #pragma unroll
        for (int kk = 0; kk < 16; kk++) {
            const float4 av = *(const float4*)&a_s[kk*64 + ty*4];
            const float4 bv = *(const float4*)&b_s[kk*64 + tx*4];
            const float aa[4] = {av.x, av.y, av.z, av.w};
            const float bb[4] = {bv.x, bv.y, bv.z, bv.w};
            #pragma unroll
            for (int i = 0; i < 4; i++)
                #pragma unroll
                for (int j = 0; j < 4; j++)
                    acc[i][j] = fmaf(aa[i], bb[j], acc[i][j]);
        }
    }
    const float4 b4 = *(const float4*)&bias[bn0 + tx*4];
    const float bc[4] = {b4.x, b4.y, b4.z, b4.w};
    #pragma unroll
    for (int i = 0; i < 4; i++) {
        *(float4*)&C[(size_t)(bm0 + ty*4 + i)*N + bn0 + tx*4] =
            make_float4(acc[i][0]+bc[0], acc[i][1]+bc[1], acc[i][2]+bc[2], acc[i][3]+bc[3]);
    }
}

// ---------------- GRU scan: 512 threads/batch, whh resident in registers as packed f16 -------
// whh fp32 is 786 KB > 512 KB regfile -> fp32 register residency is IMPOSSIBLE on one CU.
// f16-packed it is 393 KB = 192 half2 VGPRs/thread at 512 threads.  v_dot2_f32_f16 gives
// f32 accumulation; weights+h rounded to f16 (rel ~5e-4) feed only context_loss (2% thr).
// __launch_bounds__(512, 1): 1 block/CU under EITHER launch-bounds semantics -> 2 waves/SIMD
// -> 256 VGPR cap (prev (1024,4) clamped to 8 waves/SIMD -> 64 VGPR -> full weight spill,
// 8.5 us/step of L2 scratch replay = the 4.4 ms).
// Thread (j = tid&255, q = tid>>8) owns gate rows {j, 256+j, 512+j} x i in [128q, 128q+128).
// h: fp32 in per-thread reg (hprev), f16x2-packed in LDS for the matvec (broadcast reads).
__global__ __launch_bounds__(512, 1) void gru_kernel(
    const float* __restrict__ XP, const float* __restrict__ WHH,
    const float* __restrict__ bhh, const float* __restrict__ F,
    float* __restrict__ ctx_acc)
{
    __shared__ float part[3][2][256];
    __shared__ uint4 hpk[2][32];      // double-buffered f16x2-packed h[256]
    __shared__ float red[256];
    const int tid = threadIdx.x;
    const int b = blockIdx.x;
    const int j = tid & 255;
    const int q = tid >> 8;           // 0..1
    // preload packed weights: w*[m] = f16x2( whh[g*256+j][128q+2m], whh[g*256+j][128q+2m+1] )
    half2_t wr[64], wz[64], wn[64];
    {
        const float* rp = WHH + (size_t)j*256 + q*128;
        #pragma unroll
        for (int k = 0; k < 32; k++) {
            float4 vr = *(const float4*)(rp + 4*k);
            float4 vz = *(const float4*)(rp + 65536 + 4*k);
            float4 vn = *(const float4*)(rp + 131072 + 4*k);
            wr[2*k+0] = (half2_t){(_Float16)vr.x, (_Float16)vr.y};
            wr[2*k+1] = (half2_t){(_Float16)vr.z, (_Float16)vr.w};
            wz[2*k+0] = (half2_t){(_Float16)vz.x, (_Float16)vz.y};
            wz[2*k+1] = (half2_t){(_Float16)vz.z, (_Float16)vz.w};
            wn[2*k+0] = (half2_t){(_Float16)vn.x, (_Float16)vn.y};
            wn[2*k+1] = (half2_t){(_Float16)vn.z, (_Float16)vn.w};
        }
    }
    if (tid < 64) hpk[tid >> 5][tid & 31] = make_uint4(0u, 0u, 0u, 0u);
    const float bb0 = bhh[j], bb1 = bhh[256+j], bb2 = bhh[512+j];
    const float* xpb = XP + (size_t)b*NT*768;
    const float* fb  = F  + (size_t)b*NT*NDCB;
    float hprev = 0.0f, lsum = 0.0f;
    __syncthreads();
    int cur = 0;
    for (int t = 0; t < NT-1; t++) {
        // hoisted global loads (independent of h) — latency hidden behind phase A dot2s
        float xr = 0.f, xz = 0.f, xn = 0.f, fv = 0.f;
        if (tid < 256) {               // waves 0..3, wave-uniform branch
            const float* xp = xpb + (size_t)t*768;
            xr = xp[j]; xz = xp[256+j]; xn = xp[512+j];
            fv = fb[(size_t)(t+1)*NDCB + j];
        }
        // phase A: 192 v_dot2_f32_f16 over this thread's 128-wide i-chunk, weights in regs
        float a0=0.f, c0=0.f, a1=0.f, c1=0.f, a2=0.f, c2=0.f;
        #pragma unroll
        for (int kk = 0; kk < 16; kk++) {
            uint4 hp = hpk[cur][q*16 + kk];           // wave-uniform -> LDS broadcast
            half2_t h0 = __builtin_bit_cast(half2_t, hp.x);
            half2_t h1 = __builtin_bit_cast(half2_t, hp.y);
            half2_t h2 = __builtin_bit_cast(half2_t, hp.z);
            half2_t h3 = __builtin_bit_cast(half2_t, hp.w);
            a0 = dot2f(wr[4*kk+0], h0, a0); c0 = dot2f(wr[4*kk+1], h1, c0);
            a1 = dot2f(wz[4*kk+0], h0, a1); c1 = dot2f(wz[4*kk+1], h1, c1);
            a2 = dot2f(wn[4*kk+0], h0, a2); c2 = dot2f(wn[4*kk+1], h1, c2);
            a0 = dot2f(wr[4*kk+2], h2, a0); c0 = dot2f(wr[4*kk+3], h3, c0);
            a1 = dot2f(wz[4*kk+2], h2, a1); c1 = dot2f(wz[4*kk+3], h3, c1);
            a2 = dot2f(wn[4*kk+2], h2, a2); c2 = dot2f(wn[4*kk+3], h3, c2);
        }
        part[0][q][j] = a0 + c0; part[1][q][j] = a1 + c1; part[2][q][j] = a2 + c2;
        __syncthreads();
        // phase B: gate nonlinearities + state update (waves 0..3 only)
        if (tid < 256) {
            float ghr = part[0][0][j] + part[0][1][j] + bb0;
            float ghz = part[1][0][j] + part[1][1][j] + bb1;
            float ghn = part[2][0][j] + part[2][1][j] + bb2;
            float r = 1.0f/(1.0f + __expf(-(xr + ghr)));
            float z = 1.0f/(1.0f + __expf(-(xz + ghz)));
            float v = fmaf(r, ghn, xn);
            v = fminf(fmaxf(v, -12.0f), 12.0f);          // clamped fast tanh
            float ev = __expf(-2.0f*v);
            float n = (1.0f - ev)/(1.0f + ev);
            float hnew = (1.0f - z)*n + z*hprev;
            float d = hnew - fv;
            lsum = fmaf(d, d, lsum);
            float nb = __shfl_down(hnew, 1);             // neighbor j+1, same wave
            if (!(j & 1)) {
                half2_t p; p[0] = (_Float16)hnew; p[1] = (_Float16)nb;
                ((unsigned int*)&hpk[cur ^ 1][0])[j >> 1] = __builtin_bit_cast(unsigned int, p);
            }
            hprev = hnew;
        }
        __syncthreads();   // protects hpk[cur^1] reads and part[] overwrite next step
        cur ^= 1;
    }
    if (tid < 256) red[j] = lsum;
    __syncthreads();
    for (int off = 128; off > 0; off >>= 1) {
        if (tid < off) red[tid] += red[tid + off];
        __syncthreads();
    }
    if (tid == 0) atomicAdd(ctx_acc, red[0]);
}

// ---------------- small prep kernels ----------------
__global__ __launch_bounds__(256) void prep_kernel(
    const float* __restrict__ conv_w, float* __restrict__ w3,
    float* __restrict__ accv)
{
    int e = blockIdx.x*256 + threadIdx.x;     // < 196608
    if (e == 0) { accv[0] = 0.0f; accv[1] = 0.0f; }
    {   // w3[k][c][i] = conv_w[c][i][k]
        int k = e >> 16;
        int r = e & 65535;
        int c = r >> 8, i = r & 255;
        w3[e] = conv_w[(size_t)c*768 + i*3 + k];
    }
}

// s_c = fl32(exact sum c^2) via fp64   [LOCKED numerics]
__global__ __launch_bounds__(64) void cnorm_kernel(
    const float* __restrict__ CB, float* __restrict__ cn)
{
    const int k = blockIdx.x;
    const int lane = threadIdx.x;
    float4 v = *(const float4*)&CB[(size_t)k*NDCB + lane*4];
    double s = (double)v.x*(double)v.x + (double)v.y*(double)v.y
             + (double)v.z*(double)v.z + (double)v.w*(double)v.w;
    #pragma unroll
    for (int off = 32; off > 0; off >>= 1) s += __shfl_down(s, off);
    if (lane == 0) cn[k] = (float)s;
}

__global__ void finalize_kernel(const float* __restrict__ acc, float* __restrict__ out)
{
    if (threadIdx.x == 0) {
        float msd = acc[0] * (1.0f/4194304.0f);   // mean over 32*512*256
        float ctx = acc[1] * (1.0f/4184064.0f);   // mean over 32*511*256
        out[0] = msd;                 // commitment_loss
        out[1] = msd;                 // codebook_loss (same forward value)
        out[2] = ctx;                 // context_loss
        out[3] = 1.25f*msd + 0.1f*ctx; // vq_loss
    }
}

extern "C" void kernel_launch(void* const* d_in, const int* in_sizes, int n_in,
                              void* d_out, int out_size, void* d_ws, size_t ws_size,
                              hipStream_t stream) {
    const float* x      = (const float*)d_in[0];
    const float* w1     = (const float*)d_in[1];
    const float* b1     = (const float*)d_in[2];
    const float* w2     = (const float*)d_in[3];
    const float* b2     = (const float*)d_in[4];
    const float* conv_w = (const float*)d_in[5];
    const float* conv_b = (const float*)d_in[6];
    const float* cb     = (const float*)d_in[7];
    const float* wih    = (const float*)d_in[8];
    const float* whh    = (const float*)d_in[9];
    const float* bih    = (const float*)d_in[10];
    const float* bhh    = (const float*)d_in[11];
    float* out = (float*)d_out;

    // workspace layout (regions re-used once dead):
    //   [0,        16.7M)  feat  (fp32)          conv -> gru
    //   [16.7M,    50.3M)  h1    (fp32)          gemm1 -> gemm2
    //   [16.7M,    67.1M)  xproj (fp32, 50.3MB)  gemm3 -> gru   (overlays dead h1+h2)
    //   [50.3M,    67.1M)  h2    (fp32)          gemm2 -> conv
    //   [67.1M, ...]       cn / w3 / accv
    char* ws = (char*)d_ws;
    float*  feat   = (float*)(ws + 0);
    float*  h1     = (float*)(ws + 16777216);
    float*  xproj  = (float*)(ws + 16777216);
    float*  h2     = (float*)(ws + 50331648);
    float*  cn     = (float*)(ws + 67108864);
    float*  w3     = (float*)(ws + 67141632);
    float*  accv   = (float*)(ws + 68714496);

    float* idx_out = out;                   // 16384 indices (as float)
    float* qout    = out + 16384;           // 4,194,304 quantized
    float* louts   = out + 16384 + 4194304; // 4 scalars

    prep_kernel<<<768, 256, 0, stream>>>(conv_w, w3, accv);
    cnorm_kernel<<<NKCB, 64, 0, stream>>>(cb, cn);
    gemm_nt_f64_kernel<true ><<<dim3(NHMID/64, NROWS/64), 256, 0, stream>>>(x,  w1, b1, h1, NROWS, NHMID, NDIN);
    gemm_nt_f64_kernel<true ><<<dim3(NDCB/64,  NROWS/64), 256, 0, stream>>>(h1, w2, b2, h2, NROWS, NDCB, NHMID);
    conv3_f64_kernel<<<dim3(NDCB/64, NROWS/64), 256, 0, stream>>>(h2, w3, conv_b, feat);
    vq_kernel<<<NROWS/64, 512, 0, stream>>>(feat, cb, cn, idx_out, qout, accv);
    gemm_nt_kernel<<<dim3(768/64, NROWS/64), 256, 0, stream>>>(qout, wih, bih, xproj, NROWS, 768, NDCB);
    gru_kernel<<<NB, 512, 0, stream>>>(xproj, whh, bhh, feat, accv + 1);
    finalize_kernel<<<1, 64, 0, stream>>>(accv, louts);
}

// Round 2
// 1893.682 us; speedup vs baseline: 3.6479x; 1.5327x over previous
//
#include <hip/hip_runtime.h>
#include <math.h>

#define NB 32
#define NT 512
#define NDIN 1024
#define NDCB 256
#define NKCB 8192
#define NHMID 512
#define NROWS (NB*NT)   // 16384

typedef _Float16 half2_t __attribute__((ext_vector_type(2)));
typedef __attribute__((ext_vector_type(8))) short bf16x8;
typedef __attribute__((ext_vector_type(8))) unsigned short u16x8;
typedef __attribute__((ext_vector_type(4))) float f32x4;

__device__ __forceinline__ unsigned short f2bf(float x) {
    unsigned int u = __float_as_uint(x);
    return (unsigned short)((u + 0x7fffu + ((u >> 16) & 1u)) >> 16);   // RNE
}

#if __has_builtin(__builtin_amdgcn_fdot2)
__device__ __forceinline__ float dot2f(half2_t a, half2_t b, float c) {
    return __builtin_amdgcn_fdot2(a, b, c, false);
}
#else
__device__ __forceinline__ float dot2f(half2_t a, half2_t b, float c) {
    return fmaf((float)a[0], (float)b[0], fmaf((float)a[1], (float)b[1], c));
}
#endif

// ---------------- fp64-accumulate tiled GEMM: C = act(A(MxK) * B(NxK)^T + bias) ----------------
// fp32 in/out, fp64 accumulation: output = fl(exact), the canonical fp32 result.  [LOCKED numerics]
template<bool RELU>
__global__ __launch_bounds__(256) void gemm_nt_f64_kernel(
    const float* __restrict__ A, const float* __restrict__ Bm,
    const float* __restrict__ bias, float* __restrict__ C,
    int M, int N, int K)
{
    __shared__ double a_s[16*64];
    __shared__ double b_s[16*64];
    const int tid = threadIdx.x;
    const int bn0 = blockIdx.x * 64;
    const int bm0 = blockIdx.y * 64;
    const int lr = tid >> 2;          // 0..63
    const int kq = (tid & 3) << 2;    // 0,4,8,12
    const int tx = tid & 15, ty = tid >> 4;
    double acc[4][4] = {};
    const float* Ap = A + (size_t)(bm0 + lr) * K + kq;
    const float* Bp = Bm + (size_t)(bn0 + lr) * K + kq;
    for (int kt = 0; kt < K; kt += 16) {
        float4 a = *(const float4*)(Ap + kt);
        float4 b = *(const float4*)(Bp + kt);
        __syncthreads();
        a_s[(kq+0)*64+lr] = (double)a.x; a_s[(kq+1)*64+lr] = (double)a.y;
        a_s[(kq+2)*64+lr] = (double)a.z; a_s[(kq+3)*64+lr] = (double)a.w;
        b_s[(kq+0)*64+lr] = (double)b.x; b_s[(kq+1)*64+lr] = (double)b.y;
        b_s[(kq+2)*64+lr] = (double)b.z; b_s[(kq+3)*64+lr] = (double)b.w;
        __syncthreads();
        #pragma unroll
        for (int kk = 0; kk < 16; kk++) {
            double aa[4], bb[4];
            #pragma unroll
            for (int u = 0; u < 4; u++) { aa[u] = a_s[kk*64 + ty*4 + u]; bb[u] = b_s[kk*64 + tx*4 + u]; }
            #pragma unroll
            for (int i = 0; i < 4; i++)
                #pragma unroll
                for (int j = 0; j < 4; j++)
                    acc[i][j] = fma(aa[i], bb[j], acc[i][j]);
        }
    }
    const float4 b4 = *(const float4*)&bias[bn0 + tx*4];
    const double bc[4] = {(double)b4.x, (double)b4.y, (double)b4.z, (double)b4.w};
    #pragma unroll
    for (int i = 0; i < 4; i++) {
        float o[4];
        #pragma unroll
        for (int j = 0; j < 4; j++) {
            double v = acc[i][j] + bc[j];
            if (RELU) v = fmax(v, 0.0);
            o[j] = (float)v;
        }
        *(float4*)&C[(size_t)(bm0 + ty*4 + i)*N + bn0 + tx*4] =
            make_float4(o[0], o[1], o[2], o[3]);
    }
}

// ---------------- conv1d k=3 SAME, fp64 accumulation ----------------  [LOCKED numerics]
__global__ __launch_bounds__(256) void conv3_f64_kernel(
    const float* __restrict__ H2, const float* __restrict__ W3,
    const float* __restrict__ bias, float* __restrict__ F)
{
    __shared__ double a_s[16*68];       // [k][local row], local l <-> global bm0-1+l
    __shared__ double b_s[3][16*64];
    const int tid = threadIdx.x;
    const int bn0 = blockIdx.x * 64;
    const int bm0 = blockIdx.y * 64;
    const int lr = tid >> 2;
    const int kq = (tid & 3) << 2;
    const int tx = tid & 15, ty = tid >> 4;
    const int tmod = bm0 & (NT-1);
    const bool has_top = (tmod != 0);
    const bool has_bot = (tmod + 64 < NT);
    double acc[4][4] = {};
    for (int kt = 0; kt < NDCB; kt += 16) {
        float4 a = make_float4(0.f,0.f,0.f,0.f);
        if (lr >= 1 || has_top)
            a = *(const float4*)&H2[(size_t)(bm0 - 1 + lr)*NDCB + kt + kq];
        float4 e = make_float4(0.f,0.f,0.f,0.f);
        int l2 = 0, kq2 = 0;
        if (tid < 8) {
            l2 = 64 + (tid >> 2); kq2 = (tid & 3) << 2;
            if (l2 == 64 || has_bot)
                e = *(const float4*)&H2[(size_t)(bm0 - 1 + l2)*NDCB + kt + kq2];
        }
        float4 w[3];
        #pragma unroll
        for (int s = 0; s < 3; s++)
            w[s] = *(const float4*)&W3[(size_t)s*65536 + (size_t)(bn0 + lr)*NDCB + kt + kq];
        __syncthreads();
        a_s[(kq+0)*68+lr]=(double)a.x; a_s[(kq+1)*68+lr]=(double)a.y;
        a_s[(kq+2)*68+lr]=(double)a.z; a_s[(kq+3)*68+lr]=(double)a.w;
        if (tid < 8) {
            a_s[(kq2+0)*68+l2]=(double)e.x; a_s[(kq2+1)*68+l2]=(double)e.y;
            a_s[(kq2+2)*68+l2]=(double)e.z; a_s[(kq2+3)*68+l2]=(double)e.w;
        }
        #pragma unroll
        for (int s = 0; s < 3; s++) {
            b_s[s][(kq+0)*64+lr]=(double)w[s].x; b_s[s][(kq+1)*64+lr]=(double)w[s].y;
            b_s[s][(kq+2)*64+lr]=(double)w[s].z; b_s[s][(kq+3)*64+lr]=(double)w[s].w;
        }
        __syncthreads();
        #pragma unroll
        for (int kk = 0; kk < 16; kk++) {
            double aa[6];
            #pragma unroll
            for (int u = 0; u < 6; u++) aa[u] = a_s[kk*68 + ty*4 + u];
            #pragma unroll
            for (int s = 0; s < 3; s++) {
                double bb[4];
                #pragma unroll
                for (int u = 0; u < 4; u++) bb[u] = b_s[s][kk*64 + tx*4 + u];
                #pragma unroll
                for (int i = 0; i < 4; i++)
                    #pragma unroll
                    for (int j = 0; j < 4; j++)
                        acc[i][j] = fma(aa[i+s], bb[j], acc[i][j]);
            }
        }
    }
    const float4 b4 = *(const float4*)&bias[bn0 + tx*4];
    const double bc[4] = {(double)b4.x, (double)b4.y, (double)b4.z, (double)b4.w};
    #pragma unroll
    for (int i = 0; i < 4; i++) {
        const size_t base = (size_t)(bm0 + ty*4 + i)*NDCB + bn0 + tx*4;
        *(float4*)&F[base] = make_float4((float)(acc[i][0]+bc[0]), (float)(acc[i][1]+bc[1]),
                                         (float)(acc[i][2]+bc[2]), (float)(acc[i][3]+bc[3]));
    }
}

// ---------------- VQ: bf16 MFMA prefilter + canonical-fp32-quantized argmin on near-ties ----
// Prefilter error (bf16-rounded inputs, fp32 MFMA accum) sigma ~3e-7 vs score spread ~2e-4;
// tol widened 1e-6 -> 1e-5 (~24 sigma) so the canonical argmin is always in the candidate
// set; all near-ties rescored canonically as before.  [LOCKED numerics on the rescore path]
// LDS tiles XOR-swizzled (byte ^= (row&7)<<4): row-major 512B rows would be a 16-way bank
// conflict on ds_read_b128 (guide G4/T2).
__global__ __launch_bounds__(512) void vq_kernel(
    const float* __restrict__ F, const float* __restrict__ CB,
    const unsigned short* __restrict__ CBH,
    const float* __restrict__ cnorm, float* __restrict__ idx_out,
    float* __restrict__ qout, float* __restrict__ msd_acc)
{
    __shared__ unsigned short a_bf[64*256];   // 32 KB, swizzled bf16 F-tile
    __shared__ unsigned short b_bf[128*256];  // 64 KB, swizzled bf16 CB-chunk
    __shared__ float cn_s[128];
    __shared__ float red_v[64*64];            // top-2 per (row, entry); reused for msd reduce
    __shared__ int   red_i[64*64];
    __shared__ int   bests[64];
    __shared__ int   cand[64][12];
    __shared__ int   ccnt[64];
    const int tid = threadIdx.x;
    const int m0 = blockIdx.x * 64;

    // ---- stage A once: F[m0..m0+64) x 256 -> bf16, swizzled ----
    #pragma unroll
    for (int u = 0; u < 4; u++) {
        int e = tid + u*512;                 // < 2048
        int row = e >> 5, c = e & 31;
        const float* src = &F[(size_t)(m0+row)*NDCB + c*8];
        float4 f0 = *(const float4*)src;
        float4 f1 = *(const float4*)(src+4);
        u16x8 p;
        p[0]=f2bf(f0.x); p[1]=f2bf(f0.y); p[2]=f2bf(f0.z); p[3]=f2bf(f0.w);
        p[4]=f2bf(f1.x); p[5]=f2bf(f1.y); p[6]=f2bf(f1.z); p[7]=f2bf(f1.w);
        *(u16x8*)((char*)a_bf + row*512 + ((c*16) ^ ((row&7)<<4))) = p;
    }

    // wave w: rows 16*(w&3), cols 64*(w>>2) of each 64x128 chunk
    const int w = tid >> 6, lane = tid & 63;
    const int l15 = lane & 15, kg = lane >> 4;
    const int rbase = (w & 3) << 4, cbase = (w >> 2) << 6;
    const char* aP = (const char*)a_bf + (size_t)(rbase + l15)*512;
    const char* bP = (const char*)b_bf + (size_t)(cbase + l15)*512;
    const int swz = (lane & 7) << 4;

    float mv1[4], mv2[4]; int mi1[4], mi2[4];
    #pragma unroll
    for (int i = 0; i < 4; i++) { mv1[i]=3.0e38f; mv2[i]=3.0e38f; mi1[i]=0x7fffffff; mi2[i]=0x7fffffff; }

    for (int n0 = 0; n0 < NKCB; n0 += 128) {
        __syncthreads();                      // previous chunk's MFMA reads done
        #pragma unroll
        for (int u = 0; u < 8; u++) {
            int e = tid + u*512;              // < 4096
            int row = e >> 5, c = e & 31;
            u16x8 v = *(const u16x8*)&CBH[(size_t)(n0+row)*NDCB + c*8];
            *(u16x8*)((char*)b_bf + row*512 + ((c*16) ^ ((row&7)<<4))) = v;
        }
        if (tid < 128) cn_s[tid] = cnorm[n0 + tid];
        __syncthreads();
        f32x4 acc[4] = {{0.f,0.f,0.f,0.f},{0.f,0.f,0.f,0.f},{0.f,0.f,0.f,0.f},{0.f,0.f,0.f,0.f}};
        #pragma unroll
        for (int kt = 0; kt < 8; kt++) {
            const int ko = (kt*64 + kg*16) ^ swz;
            bf16x8 av = *(const bf16x8*)(aP + ko);
            #pragma unroll
            for (int f = 0; f < 4; f++) {
                bf16x8 bv = *(const bf16x8*)(bP + f*8192 + ko);
                acc[f] = __builtin_amdgcn_mfma_f32_16x16x32_bf16(av, bv, acc[f], 0, 0, 0);
            }
        }
        // epilogue: s = cn - 2*dot ; per-lane top-2.  C layout: col=lane&15, row=(lane>>4)*4+reg.
        #pragma unroll
        for (int f = 0; f < 4; f++) {
            const int col = n0 + cbase + f*16 + l15;
            const float cnv = cn_s[cbase + f*16 + l15];
            #pragma unroll
            for (int i = 0; i < 4; i++) {
                float s = fmaf(-2.0f, acc[f][i], cnv);
                if (s < mv1[i]) { mv2[i]=mv1[i]; mi2[i]=mi1[i]; mv1[i]=s; mi1[i]=col; }
                else if (s < mv2[i]) { mv2[i]=s; mi2[i]=col; }
            }
        }
    }
    #pragma unroll
    for (int i = 0; i < 4; i++) {
        const int row = rbase + kg*4 + i;
        const int eb  = (w>>2)*32 + l15*2;
        red_v[row*64 + eb]   = mv1[i]; red_i[row*64 + eb]   = mi1[i];
        red_v[row*64 + eb+1] = mv2[i]; red_i[row*64 + eb+1] = mi2[i];
    }
    __syncthreads();
    if (tid < 64) {
        float bv = 3.0e38f; int bi = 0x7fffffff;
        for (int e = 0; e < 64; e++) {
            float v = red_v[tid*64 + e]; int ii = red_i[tid*64 + e];
            if (v < bv || (v == bv && ii < bi)) { bv = v; bi = ii; }
        }
        int cnt = 0;
        for (int e = 0; e < 64; e++) {
            if (red_v[tid*64 + e] < bv + 1.0e-5f) {
                if (cnt < 12) cand[tid][cnt] = red_i[tid*64 + e];
                cnt++;
            }
        }
        bests[tid] = bi;
        ccnt[tid] = (cnt > 12) ? 12 : cnt;
    }
    __syncthreads();
    // Canonical fp32-quantized rescore of near-tie rows (one wave per row, round-robin).
    {
        const int wid = tid >> 6, lane2 = tid & 63;
        for (int r = wid; r < 64; r += 8) {
            const int nc = ccnt[r];
            if (nc < 2) continue;
            double sf = 0.0;
            #pragma unroll
            for (int u = 0; u < 4; u++) {
                double fv = (double)F[(size_t)(m0+r)*NDCB + lane2*4 + u];
                sf = fma(fv, fv, sf);
            }
            #pragma unroll
            for (int off = 32; off > 0; off >>= 1) sf += __shfl_down(sf, off);
            const float sf32 = (float)sf;          // valid on lane 0
            float bd2 = 0.0f; int bidx = 0x7fffffff;
            for (int c = 0; c < nc; c++) {
                const int k = cand[r][c];
                double g = 0.0;
                #pragma unroll
                for (int u = 0; u < 4; u++) {
                    double cv = (double)CB[(size_t)k*NDCB + lane2*4 + u];
                    double fv = (double)F[(size_t)(m0+r)*NDCB + lane2*4 + u];
                    g = fma(cv, fv, g);
                }
                #pragma unroll
                for (int off = 32; off > 0; off >>= 1) g += __shfl_down(g, off);
                if (lane2 == 0) {
                    const float G32 = (float)g;
                    const float t  = sf32 - 2.0f*G32;
                    const float d2 = t + cnorm[k];
                    if (c == 0 || d2 < bd2 || (d2 == bd2 && k < bidx)) { bd2 = d2; bidx = k; }
                }
            }
            if (lane2 == 0) bests[r] = bidx;
        }
    }
    __syncthreads();
    if (tid < 64) idx_out[m0 + tid] = (float)bests[tid];
    float lsum = 0.0f;
    #pragma unroll
    for (int s = 0; s < 8; s++) {
        int e = tid + s*512;
        int row = e >> 6, kqe = (e & 63) << 2;
        float4 q = *(const float4*)&CB[(size_t)bests[row]*NDCB + kqe];
        float4 f = *(const float4*)&F[(size_t)(m0+row)*NDCB + kqe];
        float dx=f.x-q.x, dy=f.y-q.y, dz=f.z-q.z, dw=f.w-q.w;
        lsum += dx*dx + dy*dy + dz*dz + dw*dw;
        *(float4*)&qout[(size_t)(m0+row)*NDCB + kqe] = q;
    }
    red_v[tid] = lsum;
    __syncthreads();
    for (int off = 256; off > 0; off >>= 1) {
        if (tid < off) red_v[tid] += red_v[tid + off];
        __syncthreads();
    }
    if (tid == 0) atomicAdd(msd_acc, red_v[0]);
}

// ---------------- fp32 tiled GEMM for xproj (feeds GRU/context_loss, 2% threshold) ------------
__global__ __launch_bounds__(256) void gemm_nt_kernel(
    const float* __restrict__ A, const float* __restrict__ Bm,
    const float* __restrict__ bias, float* __restrict__ C,
    int M, int N, int K)
{
    __shared__ float a_s[16*64];
    __shared__ float b_s[16*64];
    const int tid = threadIdx.x;
    const int bn0 = blockIdx.x * 64;
    const int bm0 = blockIdx.y * 64;
    const int lr = tid >> 2;
    const int kq = (tid & 3) << 2;
    const int tx = tid & 15, ty = tid >> 4;
    float acc[4][4] = {};
    const float* Ap = A + (size_t)(bm0 + lr) * K + kq;
    const float* Bp = Bm + (size_t)(bn0 + lr) * K + kq;
    for (int kt = 0; kt < K; kt += 16) {
        float4 a = *(const float4*)(Ap + kt);
        float4 b = *(const float4*)(Bp + kt);
        __syncthreads();
        a_s[(kq+0)*64+lr] = a.x; a_s[(kq+1)*64+lr] = a.y;
        a_s[(kq+2)*64+lr] = a.z; a_s[(kq+3)*64+lr] = a.w;
        b_s[(kq+0)*64+lr] = b.x; b_s[(kq+1)*64+lr] = b.y;
        b_s[(kq+2)*64+lr] = b.z; b_s[(kq+3)*64+lr] = b.w;
        __syncthreads();
        #pragma unroll
        for (int kk = 0; kk < 16; kk++) {
            const float4 av = *(const float4*)&a_s[kk*64 + ty*4];
            const float4 bv = *(const float4*)&b_s[kk*64 + tx*4];
            const float aa[4] = {av.x, av.y, av.z, av.w};
            const float bb[4] = {bv.x, bv.y, bv.z, bv.w};
            #pragma unroll
            for (int i = 0; i < 4; i++)
                #pragma unroll
                for (int j = 0; j < 4; j++)
                    acc[i][j] = fmaf(aa[i], bb[j], acc[i][j]);
        }
    }
    const float4 b4 = *(const float4*)&bias[bn0 + tx*4];
    const float bc[4] = {b4.x, b4.y, b4.z, b4.w};
    #pragma unroll
    for (int i = 0; i < 4; i++) {
        *(float4*)&C[(size_t)(bm0 + ty*4 + i)*N + bn0 + tx*4] =
            make_float4(acc[i][0]+bc[0], acc[i][1]+bc[1], acc[i][2]+bc[2], acc[i][3]+bc[3]);
    }
}

// ---------------- GRU scan: 512 threads/batch, whh resident in registers as packed f16 -------
__global__ __launch_bounds__(512, 1) void gru_kernel(
    const float* __restrict__ XP, const float* __restrict__ WHH,
    const float* __restrict__ bhh, const float* __restrict__ F,
    float* __restrict__ ctx_acc)
{
    __shared__ float part[3][2][256];
    __shared__ uint4 hpk[2][32];      // double-buffered f16x2-packed h[256]
    __shared__ float red[256];
    const int tid = threadIdx.x;
    const int b = blockIdx.x;
    const int j = tid & 255;
    const int q = tid >> 8;           // 0..1
    half2_t wr[64], wz[64], wn[64];
    {
        const float* rp = WHH + (size_t)j*256 + q*128;
        #pragma unroll
        for (int k = 0; k < 32; k++) {
            float4 vr = *(const float4*)(rp + 4*k);
            float4 vz = *(const float4*)(rp + 65536 + 4*k);
            float4 vn = *(const float4*)(rp + 131072 + 4*k);
            wr[2*k+0] = (half2_t){(_Float16)vr.x, (_Float16)vr.y};
            wr[2*k+1] = (half2_t){(_Float16)vr.z, (_Float16)vr.w};
            wz[2*k+0] = (half2_t){(_Float16)vz.x, (_Float16)vz.y};
            wz[2*k+1] = (half2_t){(_Float16)vz.z, (_Float16)vz.w};
            wn[2*k+0] = (half2_t){(_Float16)vn.x, (_Float16)vn.y};
            wn[2*k+1] = (half2_t){(_Float16)vn.z, (_Float16)vn.w};
        }
    }
    if (tid < 64) hpk[tid >> 5][tid & 31] = make_uint4(0u, 0u, 0u, 0u);
    const float bb0 = bhh[j], bb1 = bhh[256+j], bb2 = bhh[512+j];
    const float* xpb = XP + (size_t)b*NT*768;
    const float* fb  = F  + (size_t)b*NT*NDCB;
    float hprev = 0.0f, lsum = 0.0f;
    __syncthreads();
    int cur = 0;
    for (int t = 0; t < NT-1; t++) {
        float xr = 0.f, xz = 0.f, xn = 0.f, fv = 0.f;
        if (tid < 256) {               // waves 0..3, wave-uniform branch
            const float* xp = xpb + (size_t)t*768;
            xr = xp[j]; xz = xp[256+j]; xn = xp[512+j];
            fv = fb[(size_t)(t+1)*NDCB + j];
        }
        float a0=0.f, c0=0.f, a1=0.f, c1=0.f, a2=0.f, c2=0.f;
        #pragma unroll
        for (int kk = 0; kk < 16; kk++) {
            uint4 hp = hpk[cur][q*16 + kk];           // wave-uniform -> LDS broadcast
            half2_t h0 = __builtin_bit_cast(half2_t, hp.x);
            half2_t h1 = __builtin_bit_cast(half2_t, hp.y);
            half2_t h2 = __builtin_bit_cast(half2_t, hp.z);
            half2_t h3 = __builtin_bit_cast(half2_t, hp.w);
            a0 = dot2f(wr[4*kk+0], h0, a0); c0 = dot2f(wr[4*kk+1], h1, c0);
            a1 = dot2f(wz[4*kk+0], h0, a1); c1 = dot2f(wz[4*kk+1], h1, c1);
            a2 = dot2f(wn[4*kk+0], h0, a2); c2 = dot2f(wn[4*kk+1], h1, c2);
            a0 = dot2f(wr[4*kk+2], h2, a0); c0 = dot2f(wr[4*kk+3], h3, c0);
            a1 = dot2f(wz[4*kk+2], h2, a1); c1 = dot2f(wz[4*kk+3], h3, c1);
            a2 = dot2f(wn[4*kk+2], h2, a2); c2 = dot2f(wn[4*kk+3], h3, c2);
        }
        part[0][q][j] = a0 + c0; part[1][q][j] = a1 + c1; part[2][q][j] = a2 + c2;
        __syncthreads();
        if (tid < 256) {
            float ghr = part[0][0][j] + part[0][1][j] + bb0;
            float ghz = part[1][0][j] + part[1][1][j] + bb1;
            float ghn = part[2][0][j] + part[2][1][j] + bb2;
            float r = 1.0f/(1.0f + __expf(-(xr + ghr)));
            float z = 1.0f/(1.0f + __expf(-(xz + ghz)));
            float v = fmaf(r, ghn, xn);
            v = fminf(fmaxf(v, -12.0f), 12.0f);          // clamped fast tanh
            float ev = __expf(-2.0f*v);
            float n = (1.0f - ev)/(1.0f + ev);
            float hnew = (1.0f - z)*n + z*hprev;
            float d = hnew - fv;
            lsum = fmaf(d, d, lsum);
            float nb = __shfl_down(hnew, 1);             // neighbor j+1, same wave
            if (!(j & 1)) {
                half2_t p; p[0] = (_Float16)hnew; p[1] = (_Float16)nb;
                ((unsigned int*)&hpk[cur ^ 1][0])[j >> 1] = __builtin_bit_cast(unsigned int, p);
            }
            hprev = hnew;
        }
        __syncthreads();
        cur ^= 1;
    }
    if (tid < 256) red[j] = lsum;
    __syncthreads();
    for (int off = 128; off > 0; off >>= 1) {
        if (tid < off) red[tid] += red[tid + off];
        __syncthreads();
    }
    if (tid == 0) atomicAdd(ctx_acc, red[0]);
}

// ---------------- small prep kernels ----------------
__global__ __launch_bounds__(256) void prep_kernel(
    const float* __restrict__ conv_w, float* __restrict__ w3,
    float* __restrict__ accv)
{
    int e = blockIdx.x*256 + threadIdx.x;     // < 196608
    if (e == 0) { accv[0] = 0.0f; accv[1] = 0.0f; }
    {   // w3[k][c][i] = conv_w[c][i][k]
        int k = e >> 16;
        int r = e & 65535;
        int c = r >> 8, i = r & 255;
        w3[e] = conv_w[(size_t)c*768 + i*3 + k];
    }
}

// codebook fp32 -> bf16 (RNE), for the MFMA prefilter
__global__ __launch_bounds__(256) void cb2bf_kernel(
    const float* __restrict__ cb, unsigned short* __restrict__ cbh)
{
    int e = (blockIdx.x*256 + threadIdx.x) * 4;   // 2,097,152 elems / 4
    float4 v = *(const float4*)&cb[e];
    unsigned short p0 = f2bf(v.x), p1 = f2bf(v.y), p2 = f2bf(v.z), p3 = f2bf(v.w);
    unsigned long long pk = (unsigned long long)p0 | ((unsigned long long)p1 << 16)
                          | ((unsigned long long)p2 << 32) | ((unsigned long long)p3 << 48);
    *(unsigned long long*)&cbh[e] = pk;
}

// s_c = fl32(exact sum c^2) via fp64   [LOCKED numerics]
__global__ __launch_bounds__(64) void cnorm_kernel(
    const float* __restrict__ CB, float* __restrict__ cn)
{
    const int k = blockIdx.x;
    const int lane = threadIdx.x;
    float4 v = *(const float4*)&CB[(size_t)k*NDCB + lane*4];
    double s = (double)v.x*(double)v.x + (double)v.y*(double)v.y
             + (double)v.z*(double)v.z + (double)v.w*(double)v.w;
    #pragma unroll
    for (int off = 32; off > 0; off >>= 1) s += __shfl_down(s, off);
    if (lane == 0) cn[k] = (float)s;
}

__global__ void finalize_kernel(const float* __restrict__ acc, float* __restrict__ out)
{
    if (threadIdx.x == 0) {
        float msd = acc[0] * (1.0f/4194304.0f);   // mean over 32*512*256
        float ctx = acc[1] * (1.0f/4184064.0f);   // mean over 32*511*256
        out[0] = msd;                 // commitment_loss
        out[1] = msd;                 // codebook_loss (same forward value)
        out[2] = ctx;                 // context_loss
        out[3] = 1.25f*msd + 0.1f*ctx; // vq_loss
    }
}

extern "C" void kernel_launch(void* const* d_in, const int* in_sizes, int n_in,
                              void* d_out, int out_size, void* d_ws, size_t ws_size,
                              hipStream_t stream) {
    const float* x      = (const float*)d_in[0];
    const float* w1     = (const float*)d_in[1];
    const float* b1     = (const float*)d_in[2];
    const float* w2     = (const float*)d_in[3];
    const float* b2     = (const float*)d_in[4];
    const float* conv_w = (const float*)d_in[5];
    const float* conv_b = (const float*)d_in[6];
    const float* cb     = (const float*)d_in[7];
    const float* wih    = (const float*)d_in[8];
    const float* whh    = (const float*)d_in[9];
    const float* bih    = (const float*)d_in[10];
    const float* bhh    = (const float*)d_in[11];
    float* out = (float*)d_out;

    // workspace layout (regions re-used once dead):
    //   [0,        16.7M)  feat  (fp32)          conv -> gru
    //   [16.7M,    50.3M)  h1    (fp32)          gemm1 -> gemm2
    //   [16.7M,    67.1M)  xproj (fp32, 50.3MB)  gemm3 -> gru   (overlays dead h1+h2)
    //   [50.3M,    67.1M)  h2    (fp32)          gemm2 -> conv
    //   [50.3M,    54.5M)  cbh   (bf16, 4MB)     cb2bf -> vq    (overlays dead h2)
    //   [67.1M, ...]       cn / w3 / accv
    char* ws = (char*)d_ws;
    float*  feat   = (float*)(ws + 0);
    float*  h1     = (float*)(ws + 16777216);
    float*  xproj  = (float*)(ws + 16777216);
    float*  h2     = (float*)(ws + 50331648);
    unsigned short* cbh = (unsigned short*)(ws + 50331648);
    float*  cn     = (float*)(ws + 67108864);
    float*  w3     = (float*)(ws + 67141632);
    float*  accv   = (float*)(ws + 68714496);

    float* idx_out = out;                   // 16384 indices (as float)
    float* qout    = out + 16384;           // 4,194,304 quantized
    float* louts   = out + 16384 + 4194304; // 4 scalars

    prep_kernel<<<768, 256, 0, stream>>>(conv_w, w3, accv);
    cnorm_kernel<<<NKCB, 64, 0, stream>>>(cb, cn);
    gemm_nt_f64_kernel<true ><<<dim3(NHMID/64, NROWS/64), 256, 0, stream>>>(x,  w1, b1, h1, NROWS, NHMID, NDIN);
    gemm_nt_f64_kernel<true ><<<dim3(NDCB/64,  NROWS/64), 256, 0, stream>>>(h1, w2, b2, h2, NROWS, NDCB, NHMID);
    conv3_f64_kernel<<<dim3(NDCB/64, NROWS/64), 256, 0, stream>>>(h2, w3, conv_b, feat);
    cb2bf_kernel<<<2048, 256, 0, stream>>>(cb, cbh);   // after conv3: overlays dead h2
    vq_kernel<<<NROWS/64, 512, 0, stream>>>(feat, cb, cbh, cn, idx_out, qout, accv);
    gemm_nt_kernel<<<dim3(768/64, NROWS/64), 256, 0, stream>>>(qout, wih, bih, xproj, NROWS, 768, NDCB);
    gru_kernel<<<NB, 512, 0, stream>>>(xproj, whh, bhh, feat, accv + 1);
    finalize_kernel<<<1, 64, 0, stream>>>(accv, louts);
}

// Round 3
// 1785.447 us; speedup vs baseline: 3.8690x; 1.0606x over previous
//
#include <hip/hip_runtime.h>
#include <math.h>

#define NB 32
#define NT 512
#define NDIN 1024
#define NDCB 256
#define NKCB 8192
#define NHMID 512
#define NROWS (NB*NT)   // 16384

typedef _Float16 half2_t __attribute__((ext_vector_type(2)));
typedef _Float16 f16x8 __attribute__((ext_vector_type(8)));
typedef __attribute__((ext_vector_type(8))) short bf16x8;
typedef __attribute__((ext_vector_type(8))) unsigned short u16x8;
typedef __attribute__((ext_vector_type(4))) float f32x4;

__device__ __forceinline__ unsigned short f2bf(float x) {
    unsigned int u = __float_as_uint(x);
    return (unsigned short)((u + 0x7fffu + ((u >> 16) & 1u)) >> 16);   // RNE
}

#if __has_builtin(__builtin_amdgcn_fdot2)
__device__ __forceinline__ float dot2f(half2_t a, half2_t b, float c) {
    return __builtin_amdgcn_fdot2(a, b, c, false);
}
#else
__device__ __forceinline__ float dot2f(half2_t a, half2_t b, float c) {
    return fmaf((float)a[0], (float)b[0], fmaf((float)a[1], (float)b[1], c));
}
#endif

// ---------------- fp64-accumulate tiled GEMM: C = act(A(MxK) * B(NxK)^T + bias) ----------------
// fp32 in/out, fp64 accumulation: output = fl(exact), the canonical fp32 result.  [LOCKED numerics]
template<bool RELU>
__global__ __launch_bounds__(256) void gemm_nt_f64_kernel(
    const float* __restrict__ A, const float* __restrict__ Bm,
    const float* __restrict__ bias, float* __restrict__ C,
    int M, int N, int K)
{
    __shared__ double a_s[16*64];
    __shared__ double b_s[16*64];
    const int tid = threadIdx.x;
    const int bn0 = blockIdx.x * 64;
    const int bm0 = blockIdx.y * 64;
    const int lr = tid >> 2;          // 0..63
    const int kq = (tid & 3) << 2;    // 0,4,8,12
    const int tx = tid & 15, ty = tid >> 4;
    double acc[4][4] = {};
    const float* Ap = A + (size_t)(bm0 + lr) * K + kq;
    const float* Bp = Bm + (size_t)(bn0 + lr) * K + kq;
    for (int kt = 0; kt < K; kt += 16) {
        float4 a = *(const float4*)(Ap + kt);
        float4 b = *(const float4*)(Bp + kt);
        __syncthreads();
        a_s[(kq+0)*64+lr] = (double)a.x; a_s[(kq+1)*64+lr] = (double)a.y;
        a_s[(kq+2)*64+lr] = (double)a.z; a_s[(kq+3)*64+lr] = (double)a.w;
        b_s[(kq+0)*64+lr] = (double)b.x; b_s[(kq+1)*64+lr] = (double)b.y;
        b_s[(kq+2)*64+lr] = (double)b.z; b_s[(kq+3)*64+lr] = (double)b.w;
        __syncthreads();
        #pragma unroll
        for (int kk = 0; kk < 16; kk++) {
            double aa[4], bb[4];
            #pragma unroll
            for (int u = 0; u < 4; u++) { aa[u] = a_s[kk*64 + ty*4 + u]; bb[u] = b_s[kk*64 + tx*4 + u]; }
            #pragma unroll
            for (int i = 0; i < 4; i++)
                #pragma unroll
                for (int j = 0; j < 4; j++)
                    acc[i][j] = fma(aa[i], bb[j], acc[i][j]);
        }
    }
    const float4 b4 = *(const float4*)&bias[bn0 + tx*4];
    const double bc[4] = {(double)b4.x, (double)b4.y, (double)b4.z, (double)b4.w};
    #pragma unroll
    for (int i = 0; i < 4; i++) {
        float o[4];
        #pragma unroll
        for (int j = 0; j < 4; j++) {
            double v = acc[i][j] + bc[j];
            if (RELU) v = fmax(v, 0.0);
            o[j] = (float)v;
        }
        *(float4*)&C[(size_t)(bm0 + ty*4 + i)*N + bn0 + tx*4] =
            make_float4(o[0], o[1], o[2], o[3]);
    }
}

// ---------------- conv1d k=3 SAME, fp64 accumulation ----------------  [LOCKED numerics]
__global__ __launch_bounds__(256) void conv3_f64_kernel(
    const float* __restrict__ H2, const float* __restrict__ W3,
    const float* __restrict__ bias, float* __restrict__ F)
{
    __shared__ double a_s[16*68];       // [k][local row], local l <-> global bm0-1+l
    __shared__ double b_s[3][16*64];
    const int tid = threadIdx.x;
    const int bn0 = blockIdx.x * 64;
    const int bm0 = blockIdx.y * 64;
    const int lr = tid >> 2;
    const int kq = (tid & 3) << 2;
    const int tx = tid & 15, ty = tid >> 4;
    const int tmod = bm0 & (NT-1);
    const bool has_top = (tmod != 0);
    const bool has_bot = (tmod + 64 < NT);
    double acc[4][4] = {};
    for (int kt = 0; kt < NDCB; kt += 16) {
        float4 a = make_float4(0.f,0.f,0.f,0.f);
        if (lr >= 1 || has_top)
            a = *(const float4*)&H2[(size_t)(bm0 - 1 + lr)*NDCB + kt + kq];
        float4 e = make_float4(0.f,0.f,0.f,0.f);
        int l2 = 0, kq2 = 0;
        if (tid < 8) {
            l2 = 64 + (tid >> 2); kq2 = (tid & 3) << 2;
            if (l2 == 64 || has_bot)
                e = *(const float4*)&H2[(size_t)(bm0 - 1 + l2)*NDCB + kt + kq2];
        }
        float4 w[3];
        #pragma unroll
        for (int s = 0; s < 3; s++)
            w[s] = *(const float4*)&W3[(size_t)s*65536 + (size_t)(bn0 + lr)*NDCB + kt + kq];
        __syncthreads();
        a_s[(kq+0)*68+lr]=(double)a.x; a_s[(kq+1)*68+lr]=(double)a.y;
        a_s[(kq+2)*68+lr]=(double)a.z; a_s[(kq+3)*68+lr]=(double)a.w;
        if (tid < 8) {
            a_s[(kq2+0)*68+l2]=(double)e.x; a_s[(kq2+1)*68+l2]=(double)e.y;
            a_s[(kq2+2)*68+l2]=(double)e.z; a_s[(kq2+3)*68+l2]=(double)e.w;
        }
        #pragma unroll
        for (int s = 0; s < 3; s++) {
            b_s[s][(kq+0)*64+lr]=(double)w[s].x; b_s[s][(kq+1)*64+lr]=(double)w[s].y;
            b_s[s][(kq+2)*64+lr]=(double)w[s].z; b_s[s][(kq+3)*64+lr]=(double)w[s].w;
        }
        __syncthreads();
        #pragma unroll
        for (int kk = 0; kk < 16; kk++) {
            double aa[6];
            #pragma unroll
            for (int u = 0; u < 6; u++) aa[u] = a_s[kk*68 + ty*4 + u];
            #pragma unroll
            for (int s = 0; s < 3; s++) {
                double bb[4];
                #pragma unroll
                for (int u = 0; u < 4; u++) bb[u] = b_s[s][kk*64 + tx*4 + u];
                #pragma unroll
                for (int i = 0; i < 4; i++)
                    #pragma unroll
                    for (int j = 0; j < 4; j++)
                        acc[i][j] = fma(aa[i+s], bb[j], acc[i][j]);
            }
        }
    }
    const float4 b4 = *(const float4*)&bias[bn0 + tx*4];
    const double bc[4] = {(double)b4.x, (double)b4.y, (double)b4.z, (double)b4.w};
    #pragma unroll
    for (int i = 0; i < 4; i++) {
        const size_t base = (size_t)(bm0 + ty*4 + i)*NDCB + bn0 + tx*4;
        *(float4*)&F[base] = make_float4((float)(acc[i][0]+bc[0]), (float)(acc[i][1]+bc[1]),
                                         (float)(acc[i][2]+bc[2]), (float)(acc[i][3]+bc[3]));
    }
}

// ---------------- VQ: bf16 MFMA prefilter + canonical-fp32-quantized argmin on near-ties ----
// Prefilter error sigma ~3e-7 vs score spread ~2e-4; tol 1e-5 (~24 sigma); near-ties
// rescored canonically.  [LOCKED numerics on the rescore path]
__global__ __launch_bounds__(512) void vq_kernel(
    const float* __restrict__ F, const float* __restrict__ CB,
    const unsigned short* __restrict__ CBH,
    const float* __restrict__ cnorm, float* __restrict__ idx_out,
    float* __restrict__ qout, float* __restrict__ msd_acc)
{
    __shared__ unsigned short a_bf[64*256];   // 32 KB, swizzled bf16 F-tile
    __shared__ unsigned short b_bf[128*256];  // 64 KB, swizzled bf16 CB-chunk
    __shared__ float cn_s[128];
    __shared__ float red_v[64*64];            // top-2 per (row, entry); reused for msd reduce
    __shared__ int   red_i[64*64];
    __shared__ int   bests[64];
    __shared__ int   cand[64][12];
    __shared__ int   ccnt[64];
    const int tid = threadIdx.x;
    const int m0 = blockIdx.x * 64;

    // ---- stage A once: F[m0..m0+64) x 256 -> bf16, swizzled ----
    #pragma unroll
    for (int u = 0; u < 4; u++) {
        int e = tid + u*512;                 // < 2048
        int row = e >> 5, c = e & 31;
        const float* src = &F[(size_t)(m0+row)*NDCB + c*8];
        float4 f0 = *(const float4*)src;
        float4 f1 = *(const float4*)(src+4);
        u16x8 p;
        p[0]=f2bf(f0.x); p[1]=f2bf(f0.y); p[2]=f2bf(f0.z); p[3]=f2bf(f0.w);
        p[4]=f2bf(f1.x); p[5]=f2bf(f1.y); p[6]=f2bf(f1.z); p[7]=f2bf(f1.w);
        *(u16x8*)((char*)a_bf + row*512 + ((c*16) ^ ((row&7)<<4))) = p;
    }

    // wave w: rows 16*(w&3), cols 64*(w>>2) of each 64x128 chunk
    const int w = tid >> 6, lane = tid & 63;
    const int l15 = lane & 15, kg = lane >> 4;
    const int rbase = (w & 3) << 4, cbase = (w >> 2) << 6;
    const char* aP = (const char*)a_bf + (size_t)(rbase + l15)*512;
    const char* bP = (const char*)b_bf + (size_t)(cbase + l15)*512;
    const int swz = (lane & 7) << 4;

    float mv1[4], mv2[4]; int mi1[4], mi2[4];
    #pragma unroll
    for (int i = 0; i < 4; i++) { mv1[i]=3.0e38f; mv2[i]=3.0e38f; mi1[i]=0x7fffffff; mi2[i]=0x7fffffff; }

    for (int n0 = 0; n0 < NKCB; n0 += 128) {
        __syncthreads();                      // previous chunk's MFMA reads done
        #pragma unroll
        for (int u = 0; u < 8; u++) {
            int e = tid + u*512;              // < 4096
            int row = e >> 5, c = e & 31;
            u16x8 v = *(const u16x8*)&CBH[(size_t)(n0+row)*NDCB + c*8];
            *(u16x8*)((char*)b_bf + row*512 + ((c*16) ^ ((row&7)<<4))) = v;
        }
        if (tid < 128) cn_s[tid] = cnorm[n0 + tid];
        __syncthreads();
        f32x4 acc[4] = {{0.f,0.f,0.f,0.f},{0.f,0.f,0.f,0.f},{0.f,0.f,0.f,0.f},{0.f,0.f,0.f,0.f}};
        #pragma unroll
        for (int kt = 0; kt < 8; kt++) {
            const int ko = (kt*64 + kg*16) ^ swz;
            bf16x8 av = *(const bf16x8*)(aP + ko);
            #pragma unroll
            for (int f = 0; f < 4; f++) {
                bf16x8 bv = *(const bf16x8*)(bP + f*8192 + ko);
                acc[f] = __builtin_amdgcn_mfma_f32_16x16x32_bf16(av, bv, acc[f], 0, 0, 0);
            }
        }
        // epilogue: s = cn - 2*dot ; per-lane top-2.  C layout: col=lane&15, row=(lane>>4)*4+reg.
        #pragma unroll
        for (int f = 0; f < 4; f++) {
            const int col = n0 + cbase + f*16 + l15;
            const float cnv = cn_s[cbase + f*16 + l15];
            #pragma unroll
            for (int i = 0; i < 4; i++) {
                float s = fmaf(-2.0f, acc[f][i], cnv);
                if (s < mv1[i]) { mv2[i]=mv1[i]; mi2[i]=mi1[i]; mv1[i]=s; mi1[i]=col; }
                else if (s < mv2[i]) { mv2[i]=s; mi2[i]=col; }
            }
        }
    }
    #pragma unroll
    for (int i = 0; i < 4; i++) {
        const int row = rbase + kg*4 + i;
        const int eb  = (w>>2)*32 + l15*2;
        red_v[row*64 + eb]   = mv1[i]; red_i[row*64 + eb]   = mi1[i];
        red_v[row*64 + eb+1] = mv2[i]; red_i[row*64 + eb+1] = mi2[i];
    }
    __syncthreads();
    if (tid < 64) {
        float bv = 3.0e38f; int bi = 0x7fffffff;
        for (int e = 0; e < 64; e++) {
            float v = red_v[tid*64 + e]; int ii = red_i[tid*64 + e];
            if (v < bv || (v == bv && ii < bi)) { bv = v; bi = ii; }
        }
        int cnt = 0;
        for (int e = 0; e < 64; e++) {
            if (red_v[tid*64 + e] < bv + 1.0e-5f) {
                if (cnt < 12) cand[tid][cnt] = red_i[tid*64 + e];
                cnt++;
            }
        }
        bests[tid] = bi;
        ccnt[tid] = (cnt > 12) ? 12 : cnt;
    }
    __syncthreads();
    // Canonical fp32-quantized rescore of near-tie rows (one wave per row, round-robin).
    {
        const int wid = tid >> 6, lane2 = tid & 63;
        for (int r = wid; r < 64; r += 8) {
            const int nc = ccnt[r];
            if (nc < 2) continue;
            double sf = 0.0;
            #pragma unroll
            for (int u = 0; u < 4; u++) {
                double fv = (double)F[(size_t)(m0+r)*NDCB + lane2*4 + u];
                sf = fma(fv, fv, sf);
            }
            #pragma unroll
            for (int off = 32; off > 0; off >>= 1) sf += __shfl_down(sf, off);
            const float sf32 = (float)sf;          // valid on lane 0
            float bd2 = 0.0f; int bidx = 0x7fffffff;
            for (int c = 0; c < nc; c++) {
                const int k = cand[r][c];
                double g = 0.0;
                #pragma unroll
                for (int u = 0; u < 4; u++) {
                    double cv = (double)CB[(size_t)k*NDCB + lane2*4 + u];
                    double fv = (double)F[(size_t)(m0+r)*NDCB + lane2*4 + u];
                    g = fma(cv, fv, g);
                }
                #pragma unroll
                for (int off = 32; off > 0; off >>= 1) g += __shfl_down(g, off);
                if (lane2 == 0) {
                    const float G32 = (float)g;
                    const float t  = sf32 - 2.0f*G32;
                    const float d2 = t + cnorm[k];
                    if (c == 0 || d2 < bd2 || (d2 == bd2 && k < bidx)) { bd2 = d2; bidx = k; }
                }
            }
            if (lane2 == 0) bests[r] = bidx;
        }
    }
    __syncthreads();
    if (tid < 64) idx_out[m0 + tid] = (float)bests[tid];
    float lsum = 0.0f;
    #pragma unroll
    for (int s = 0; s < 8; s++) {
        int e = tid + s*512;
        int row = e >> 6, kqe = (e & 63) << 2;
        float4 q = *(const float4*)&CB[(size_t)bests[row]*NDCB + kqe];
        float4 f = *(const float4*)&F[(size_t)(m0+row)*NDCB + kqe];
        float dx=f.x-q.x, dy=f.y-q.y, dz=f.z-q.z, dw=f.w-q.w;
        lsum += dx*dx + dy*dy + dz*dz + dw*dw;
        *(float4*)&qout[(size_t)(m0+row)*NDCB + kqe] = q;
    }
    red_v[tid] = lsum;
    __syncthreads();
    for (int off = 256; off > 0; off >>= 1) {
        if (tid < off) red_v[tid] += red_v[tid + off];
        __syncthreads();
    }
    if (tid == 0) atomicAdd(msd_acc, red_v[0]);
}

// ---------------- xproj: f16 MFMA GEMM (feeds GRU/context_loss, 2% threshold) ----------------
// A = qout * 2^13 (exact scaling lifts +-1.2e-4 codebook values out of f16-subnormal range),
// B = wih pre-converted to f16, fp32 accumulate, epilogue acc*2^-13 + bias.
// Rel err ~5e-4 — same class as the GRU's f16 whh.  Structure cloned from vq_kernel.
__global__ __launch_bounds__(512) void xproj_mfma_kernel(
    const float* __restrict__ Q, const unsigned short* __restrict__ WIHH,
    const float* __restrict__ bias, float* __restrict__ C)
{
    __shared__ unsigned short a_h[64*256];    // 32 KB, swizzled f16 (q * 8192)
    __shared__ unsigned short b_h[128*256];   // 64 KB, swizzled f16 wih chunk
    const int tid = threadIdx.x;
    const int m0 = blockIdx.x * 64;

    #pragma unroll
    for (int u = 0; u < 4; u++) {
        int e = tid + u*512;                 // < 2048
        int row = e >> 5, c = e & 31;
        const float* src = &Q[(size_t)(m0+row)*NDCB + c*8];
        float4 f0 = *(const float4*)src;
        float4 f1 = *(const float4*)(src+4);
        f16x8 p;
        p[0]=(_Float16)(f0.x*8192.0f); p[1]=(_Float16)(f0.y*8192.0f);
        p[2]=(_Float16)(f0.z*8192.0f); p[3]=(_Float16)(f0.w*8192.0f);
        p[4]=(_Float16)(f1.x*8192.0f); p[5]=(_Float16)(f1.y*8192.0f);
        p[6]=(_Float16)(f1.z*8192.0f); p[7]=(_Float16)(f1.w*8192.0f);
        *(f16x8*)((char*)a_h + row*512 + ((c*16) ^ ((row&7)<<4))) = p;
    }

    const int w = tid >> 6, lane = tid & 63;
    const int l15 = lane & 15, kg = lane >> 4;
    const int rbase = (w & 3) << 4, cbase = (w >> 2) << 6;
    const char* aP = (const char*)a_h + (size_t)(rbase + l15)*512;
    const char* bP = (const char*)b_h + (size_t)(cbase + l15)*512;
    const int swz = (lane & 7) << 4;

    for (int n0 = 0; n0 < 768; n0 += 128) {
        __syncthreads();
        #pragma unroll
        for (int u = 0; u < 8; u++) {
            int e = tid + u*512;              // < 4096
            int row = e >> 5, c = e & 31;
            u16x8 v = *(const u16x8*)&WIHH[(size_t)(n0+row)*NDCB + c*8];
            *(u16x8*)((char*)b_h + row*512 + ((c*16) ^ ((row&7)<<4))) = v;
        }
        __syncthreads();
        f32x4 acc[4] = {{0.f,0.f,0.f,0.f},{0.f,0.f,0.f,0.f},{0.f,0.f,0.f,0.f},{0.f,0.f,0.f,0.f}};
        #pragma unroll
        for (int kt = 0; kt < 8; kt++) {
            const int ko = (kt*64 + kg*16) ^ swz;
            f16x8 av = *(const f16x8*)(aP + ko);
            #pragma unroll
            for (int f = 0; f < 4; f++) {
                f16x8 bv = *(const f16x8*)(bP + f*8192 + ko);
                acc[f] = __builtin_amdgcn_mfma_f32_16x16x32_f16(av, bv, acc[f], 0, 0, 0);
            }
        }
        // C layout: col=lane&15, row=(lane>>4)*4+reg
        #pragma unroll
        for (int f = 0; f < 4; f++) {
            const int col = n0 + cbase + f*16 + l15;
            const float bv = bias[col];
            #pragma unroll
            for (int i = 0; i < 4; i++) {
                const int row = m0 + rbase + kg*4 + i;
                C[(size_t)row*768 + col] = fmaf(acc[f][i], 1.0f/8192.0f, bv);
            }
        }
    }
}

// ---------------- GRU scan: 512 threads/batch, whh resident in registers as packed f16 -------
// amdgpu_waves_per_eu(2,2) pins the allocator's occupancy target to 2 waves/EU (one
// 512-thread block/CU) -> firm 256-VGPR budget.  R2's __launch_bounds__(512,1) left the
// heuristic free: it targeted 4 waves/EU (128 VGPR) and spilled ~137 regs/thread
// (WRITE_SIZE 9 MB, ~0.9us/step of L2 scratch replay = the 650us).
__global__ __launch_bounds__(512) __attribute__((amdgpu_waves_per_eu(2, 2))) void gru_kernel(
    const float* __restrict__ XP, const float* __restrict__ WHH,
    const float* __restrict__ bhh, const float* __restrict__ F,
    float* __restrict__ ctx_acc)
{
    __shared__ float part[3][2][256];
    __shared__ uint4 hpk[2][32];      // double-buffered f16x2-packed h[256]
    __shared__ float red[256];
    const int tid = threadIdx.x;
    const int b = blockIdx.x;
    const int j = tid & 255;
    const int q = tid >> 8;           // 0..1
    half2_t wr[64], wz[64], wn[64];
    {
        const float* rp = WHH + (size_t)j*256 + q*128;
        #pragma unroll
        for (int k = 0; k < 32; k++) {
            float4 vr = *(const float4*)(rp + 4*k);
            float4 vz = *(const float4*)(rp + 65536 + 4*k);
            float4 vn = *(const float4*)(rp + 131072 + 4*k);
            wr[2*k+0] = (half2_t){(_Float16)vr.x, (_Float16)vr.y};
            wr[2*k+1] = (half2_t){(_Float16)vr.z, (_Float16)vr.w};
            wz[2*k+0] = (half2_t){(_Float16)vz.x, (_Float16)vz.y};
            wz[2*k+1] = (half2_t){(_Float16)vz.z, (_Float16)vz.w};
            wn[2*k+0] = (half2_t){(_Float16)vn.x, (_Float16)vn.y};
            wn[2*k+1] = (half2_t){(_Float16)vn.z, (_Float16)vn.w};
        }
    }
    if (tid < 64) hpk[tid >> 5][tid & 31] = make_uint4(0u, 0u, 0u, 0u);
    const float bb0 = bhh[j], bb1 = bhh[256+j], bb2 = bhh[512+j];
    const float* xpb = XP + (size_t)b*NT*768;
    const float* fb  = F  + (size_t)b*NT*NDCB;
    float hprev = 0.0f, lsum = 0.0f;
    __syncthreads();
    int cur = 0;
    for (int t = 0; t < NT-1; t++) {
        float xr = 0.f, xz = 0.f, xn = 0.f, fv = 0.f;
        if (tid < 256) {               // waves 0..3, wave-uniform branch
            const float* xp = xpb + (size_t)t*768;
            xr = xp[j]; xz = xp[256+j]; xn = xp[512+j];
            fv = fb[(size_t)(t+1)*NDCB + j];
        }
        float a0=0.f, c0=0.f, a1=0.f, c1=0.f, a2=0.f, c2=0.f;
        #pragma unroll
        for (int kk = 0; kk < 16; kk++) {
            uint4 hp = hpk[cur][q*16 + kk];           // wave-uniform -> LDS broadcast
            half2_t h0 = __builtin_bit_cast(half2_t, hp.x);
            half2_t h1 = __builtin_bit_cast(half2_t, hp.y);
            half2_t h2 = __builtin_bit_cast(half2_t, hp.z);
            half2_t h3 = __builtin_bit_cast(half2_t, hp.w);
            a0 = dot2f(wr[4*kk+0], h0, a0); c0 = dot2f(wr[4*kk+1], h1, c0);
            a1 = dot2f(wz[4*kk+0], h0, a1); c1 = dot2f(wz[4*kk+1], h1, c1);
            a2 = dot2f(wn[4*kk+0], h0, a2); c2 = dot2f(wn[4*kk+1], h1, c2);
            a0 = dot2f(wr[4*kk+2], h2, a0); c0 = dot2f(wr[4*kk+3], h3, c0);
            a1 = dot2f(wz[4*kk+2], h2, a1); c1 = dot2f(wz[4*kk+3], h3, c1);
            a2 = dot2f(wn[4*kk+2], h2, a2); c2 = dot2f(wn[4*kk+3], h3, c2);
        }
        part[0][q][j] = a0 + c0; part[1][q][j] = a1 + c1; part[2][q][j] = a2 + c2;
        __syncthreads();
        if (tid < 256) {
            float ghr = part[0][0][j] + part[0][1][j] + bb0;
            float ghz = part[1][0][j] + part[1][1][j] + bb1;
            float ghn = part[2][0][j] + part[2][1][j] + bb2;
            float r = 1.0f/(1.0f + __expf(-(xr + ghr)));
            float z = 1.0f/(1.0f + __expf(-(xz + ghz)));
            float v = fmaf(r, ghn, xn);
            v = fminf(fmaxf(v, -12.0f), 12.0f);          // clamped fast tanh
            float ev = __expf(-2.0f*v);
            float n = (1.0f - ev)/(1.0f + ev);
            float hnew = (1.0f - z)*n + z*hprev;
            float d = hnew - fv;
            lsum = fmaf(d, d, lsum);
            float nb = __shfl_down(hnew, 1);             // neighbor j+1, same wave
            if (!(j & 1)) {
                half2_t p; p[0] = (_Float16)hnew; p[1] = (_Float16)nb;
                ((unsigned int*)&hpk[cur ^ 1][0])[j >> 1] = __builtin_bit_cast(unsigned int, p);
            }
            hprev = hnew;
        }
        __syncthreads();
        cur ^= 1;
    }
    if (tid < 256) red[j] = lsum;
    __syncthreads();
    for (int off = 128; off > 0; off >>= 1) {
        if (tid < off) red[tid] += red[tid + off];
        __syncthreads();
    }
    if (tid == 0) atomicAdd(ctx_acc, red[0]);
}

// ---------------- small prep kernels ----------------
__global__ __launch_bounds__(256) void prep_kernel(
    const float* __restrict__ conv_w, float* __restrict__ w3,
    const float* __restrict__ wih, unsigned short* __restrict__ wihh,
    float* __restrict__ accv)
{
    int e = blockIdx.x*256 + threadIdx.x;     // < 196608
    if (e == 0) { accv[0] = 0.0f; accv[1] = 0.0f; }
    {   // w3[k][c][i] = conv_w[c][i][k]
        int k = e >> 16;
        int r = e & 65535;
        int c = r >> 8, i = r & 255;
        w3[e] = conv_w[(size_t)c*768 + i*3 + k];
    }
    {   // wih f32 -> f16 bits (768*256 = 196608 elements, exactly this grid)
        _Float16 h = (_Float16)wih[e];
        wihh[e] = __builtin_bit_cast(unsigned short, h);
    }
}

// codebook fp32 -> bf16 (RNE), for the MFMA prefilter
__global__ __launch_bounds__(256) void cb2bf_kernel(
    const float* __restrict__ cb, unsigned short* __restrict__ cbh)
{
    int e = (blockIdx.x*256 + threadIdx.x) * 4;   // 2,097,152 elems / 4
    float4 v = *(const float4*)&cb[e];
    unsigned short p0 = f2bf(v.x), p1 = f2bf(v.y), p2 = f2bf(v.z), p3 = f2bf(v.w);
    unsigned long long pk = (unsigned long long)p0 | ((unsigned long long)p1 << 16)
                          | ((unsigned long long)p2 << 32) | ((unsigned long long)p3 << 48);
    *(unsigned long long*)&cbh[e] = pk;
}

// s_c = fl32(exact sum c^2) via fp64   [LOCKED numerics]
__global__ __launch_bounds__(64) void cnorm_kernel(
    const float* __restrict__ CB, float* __restrict__ cn)
{
    const int k = blockIdx.x;
    const int lane = threadIdx.x;
    float4 v = *(const float4*)&CB[(size_t)k*NDCB + lane*4];
    double s = (double)v.x*(double)v.x + (double)v.y*(double)v.y
             + (double)v.z*(double)v.z + (double)v.w*(double)v.w;
    #pragma unroll
    for (int off = 32; off > 0; off >>= 1) s += __shfl_down(s, off);
    if (lane == 0) cn[k] = (float)s;
}

__global__ void finalize_kernel(const float* __restrict__ acc, float* __restrict__ out)
{
    if (threadIdx.x == 0) {
        float msd = acc[0] * (1.0f/4194304.0f);   // mean over 32*512*256
        float ctx = acc[1] * (1.0f/4184064.0f);   // mean over 32*511*256
        out[0] = msd;                 // commitment_loss
        out[1] = msd;                 // codebook_loss (same forward value)
        out[2] = ctx;                 // context_loss
        out[3] = 1.25f*msd + 0.1f*ctx; // vq_loss
    }
}

extern "C" void kernel_launch(void* const* d_in, const int* in_sizes, int n_in,
                              void* d_out, int out_size, void* d_ws, size_t ws_size,
                              hipStream_t stream) {
    const float* x      = (const float*)d_in[0];
    const float* w1     = (const float*)d_in[1];
    const float* b1     = (const float*)d_in[2];
    const float* w2     = (const float*)d_in[3];
    const float* b2     = (const float*)d_in[4];
    const float* conv_w = (const float*)d_in[5];
    const float* conv_b = (const float*)d_in[6];
    const float* cb     = (const float*)d_in[7];
    const float* wih    = (const float*)d_in[8];
    const float* whh    = (const float*)d_in[9];
    const float* bih    = (const float*)d_in[10];
    const float* bhh    = (const float*)d_in[11];
    float* out = (float*)d_out;

    // workspace layout (regions re-used once dead):
    //   [0,        16.7M)  feat  (fp32)          conv -> gru
    //   [16.7M,    50.3M)  h1    (fp32)          gemm1 -> gemm2
    //   [16.7M,    67.1M)  xproj (fp32, 50.3MB)  gemm3 -> gru   (overlays dead h1+h2)
    //   [50.3M,    67.1M)  h2    (fp32)          gemm2 -> conv
    //   [50.3M,    54.5M)  cbh   (bf16, 4MB)     cb2bf -> vq    (overlays dead h2)
    //   [67.1M, ...]       cn / w3 / wihh / accv
    char* ws = (char*)d_ws;
    float*  feat   = (float*)(ws + 0);
    float*  h1     = (float*)(ws + 16777216);
    float*  xproj  = (float*)(ws + 16777216);
    float*  h2     = (float*)(ws + 50331648);
    unsigned short* cbh = (unsigned short*)(ws + 50331648);
    float*  cn     = (float*)(ws + 67108864);
    float*  w3     = (float*)(ws + 67141632);
    unsigned short* wihh = (unsigned short*)(ws + 67928064);   // 393216 B (old wht slot)
    float*  accv   = (float*)(ws + 68714496);

    float* idx_out = out;                   // 16384 indices (as float)
    float* qout    = out + 16384;           // 4,194,304 quantized
    float* louts   = out + 16384 + 4194304; // 4 scalars

    prep_kernel<<<768, 256, 0, stream>>>(conv_w, w3, wih, wihh, accv);
    cnorm_kernel<<<NKCB, 64, 0, stream>>>(cb, cn);
    gemm_nt_f64_kernel<true ><<<dim3(NHMID/64, NROWS/64), 256, 0, stream>>>(x,  w1, b1, h1, NROWS, NHMID, NDIN);
    gemm_nt_f64_kernel<true ><<<dim3(NDCB/64,  NROWS/64), 256, 0, stream>>>(h1, w2, b2, h2, NROWS, NDCB, NHMID);
    conv3_f64_kernel<<<dim3(NDCB/64, NROWS/64), 256, 0, stream>>>(h2, w3, conv_b, feat);
    cb2bf_kernel<<<2048, 256, 0, stream>>>(cb, cbh);   // after conv3: overlays dead h2
    vq_kernel<<<NROWS/64, 512, 0, stream>>>(feat, cb, cbh, cn, idx_out, qout, accv);
    xproj_mfma_kernel<<<NROWS/64, 512, 0, stream>>>(qout, wihh, bih, xproj);
    gru_kernel<<<NB, 512, 0, stream>>>(xproj, whh, bhh, feat, accv + 1);
    finalize_kernel<<<1, 64, 0, stream>>>(accv, louts);
}

// Round 4
// 1779.683 us; speedup vs baseline: 3.8815x; 1.0032x over previous
//
#include <hip/hip_runtime.h>
#include <math.h>

#define NB 32
#define NT 512
#define NDIN 1024
#define NDCB 256
#define NKCB 8192
#define NHMID 512
#define NROWS (NB*NT)   // 16384

typedef _Float16 half2_t __attribute__((ext_vector_type(2)));
typedef _Float16 f16x8 __attribute__((ext_vector_type(8)));
typedef __attribute__((ext_vector_type(8))) short bf16x8;
typedef __attribute__((ext_vector_type(8))) unsigned short u16x8;
typedef __attribute__((ext_vector_type(4))) float f32x4;

__device__ __forceinline__ unsigned short f2bf(float x) {
    unsigned int u = __float_as_uint(x);
    return (unsigned short)((u + 0x7fffu + ((u >> 16) & 1u)) >> 16);   // RNE
}

#if __has_builtin(__builtin_amdgcn_fdot2)
__device__ __forceinline__ float dot2f(half2_t a, half2_t b, float c) {
    return __builtin_amdgcn_fdot2(a, b, c, false);
}
#else
__device__ __forceinline__ float dot2f(half2_t a, half2_t b, float c) {
    return fmaf((float)a[0], (float)b[0], fmaf((float)a[1], (float)b[1], c));
}
#endif

// ---------------- fp64-accumulate tiled GEMM: C = act(A(MxK) * B(NxK)^T + bias) ----------------
// fp32 in/out, fp64 accumulation: output = fl(exact), the canonical fp32 result.  [LOCKED numerics]
template<bool RELU>
__global__ __launch_bounds__(256) void gemm_nt_f64_kernel(
    const float* __restrict__ A, const float* __restrict__ Bm,
    const float* __restrict__ bias, float* __restrict__ C,
    int M, int N, int K)
{
    __shared__ double a_s[16*64];
    __shared__ double b_s[16*64];
    const int tid = threadIdx.x;
    const int bn0 = blockIdx.x * 64;
    const int bm0 = blockIdx.y * 64;
    const int lr = tid >> 2;          // 0..63
    const int kq = (tid & 3) << 2;    // 0,4,8,12
    const int tx = tid & 15, ty = tid >> 4;
    double acc[4][4] = {};
    const float* Ap = A + (size_t)(bm0 + lr) * K + kq;
    const float* Bp = Bm + (size_t)(bn0 + lr) * K + kq;
    for (int kt = 0; kt < K; kt += 16) {
        float4 a = *(const float4*)(Ap + kt);
        float4 b = *(const float4*)(Bp + kt);
        __syncthreads();
        a_s[(kq+0)*64+lr] = (double)a.x; a_s[(kq+1)*64+lr] = (double)a.y;
        a_s[(kq+2)*64+lr] = (double)a.z; a_s[(kq+3)*64+lr] = (double)a.w;
        b_s[(kq+0)*64+lr] = (double)b.x; b_s[(kq+1)*64+lr] = (double)b.y;
        b_s[(kq+2)*64+lr] = (double)b.z; b_s[(kq+3)*64+lr] = (double)b.w;
        __syncthreads();
        #pragma unroll
        for (int kk = 0; kk < 16; kk++) {
            double aa[4], bb[4];
            #pragma unroll
            for (int u = 0; u < 4; u++) { aa[u] = a_s[kk*64 + ty*4 + u]; bb[u] = b_s[kk*64 + tx*4 + u]; }
            #pragma unroll
            for (int i = 0; i < 4; i++)
                #pragma unroll
                for (int j = 0; j < 4; j++)
                    acc[i][j] = fma(aa[i], bb[j], acc[i][j]);
        }
    }
    const float4 b4 = *(const float4*)&bias[bn0 + tx*4];
    const double bc[4] = {(double)b4.x, (double)b4.y, (double)b4.z, (double)b4.w};
    #pragma unroll
    for (int i = 0; i < 4; i++) {
        float o[4];
        #pragma unroll
        for (int j = 0; j < 4; j++) {
            double v = acc[i][j] + bc[j];
            if (RELU) v = fmax(v, 0.0);
            o[j] = (float)v;
        }
        *(float4*)&C[(size_t)(bm0 + ty*4 + i)*N + bn0 + tx*4] =
            make_float4(o[0], o[1], o[2], o[3]);
    }
}

// ---------------- conv1d k=3 SAME, fp64 accumulation ----------------  [LOCKED numerics]
__global__ __launch_bounds__(256) void conv3_f64_kernel(
    const float* __restrict__ H2, const float* __restrict__ W3,
    const float* __restrict__ bias, float* __restrict__ F)
{
    __shared__ double a_s[16*68];       // [k][local row], local l <-> global bm0-1+l
    __shared__ double b_s[3][16*64];
    const int tid = threadIdx.x;
    const int bn0 = blockIdx.x * 64;
    const int bm0 = blockIdx.y * 64;
    const int lr = tid >> 2;
    const int kq = (tid & 3) << 2;
    const int tx = tid & 15, ty = tid >> 4;
    const int tmod = bm0 & (NT-1);
    const bool has_top = (tmod != 0);
    const bool has_bot = (tmod + 64 < NT);
    double acc[4][4] = {};
    for (int kt = 0; kt < NDCB; kt += 16) {
        float4 a = make_float4(0.f,0.f,0.f,0.f);
        if (lr >= 1 || has_top)
            a = *(const float4*)&H2[(size_t)(bm0 - 1 + lr)*NDCB + kt + kq];
        float4 e = make_float4(0.f,0.f,0.f,0.f);
        int l2 = 0, kq2 = 0;
        if (tid < 8) {
            l2 = 64 + (tid >> 2); kq2 = (tid & 3) << 2;
            if (l2 == 64 || has_bot)
                e = *(const float4*)&H2[(size_t)(bm0 - 1 + l2)*NDCB + kt + kq2];
        }
        float4 w[3];
        #pragma unroll
        for (int s = 0; s < 3; s++)
            w[s] = *(const float4*)&W3[(size_t)s*65536 + (size_t)(bn0 + lr)*NDCB + kt + kq];
        __syncthreads();
        a_s[(kq+0)*68+lr]=(double)a.x; a_s[(kq+1)*68+lr]=(double)a.y;
        a_s[(kq+2)*68+lr]=(double)a.z; a_s[(kq+3)*68+lr]=(double)a.w;
        if (tid < 8) {
            a_s[(kq2+0)*68+l2]=(double)e.x; a_s[(kq2+1)*68+l2]=(double)e.y;
            a_s[(kq2+2)*68+l2]=(double)e.z; a_s[(kq2+3)*68+l2]=(double)e.w;
        }
        #pragma unroll
        for (int s = 0; s < 3; s++) {
            b_s[s][(kq+0)*64+lr]=(double)w[s].x; b_s[s][(kq+1)*64+lr]=(double)w[s].y;
            b_s[s][(kq+2)*64+lr]=(double)w[s].z; b_s[s][(kq+3)*64+lr]=(double)w[s].w;
        }
        __syncthreads();
        #pragma unroll
        for (int kk = 0; kk < 16; kk++) {
            double aa[6];
            #pragma unroll
            for (int u = 0; u < 6; u++) aa[u] = a_s[kk*68 + ty*4 + u];
            #pragma unroll
            for (int s = 0; s < 3; s++) {
                double bb[4];
                #pragma unroll
                for (int u = 0; u < 4; u++) bb[u] = b_s[s][kk*64 + tx*4 + u];
                #pragma unroll
                for (int i = 0; i < 4; i++)
                    #pragma unroll
                    for (int j = 0; j < 4; j++)
                        acc[i][j] = fma(aa[i+s], bb[j], acc[i][j]);
            }
        }
    }
    const float4 b4 = *(const float4*)&bias[bn0 + tx*4];
    const double bc[4] = {(double)b4.x, (double)b4.y, (double)b4.z, (double)b4.w};
    #pragma unroll
    for (int i = 0; i < 4; i++) {
        const size_t base = (size_t)(bm0 + ty*4 + i)*NDCB + bn0 + tx*4;
        *(float4*)&F[base] = make_float4((float)(acc[i][0]+bc[0]), (float)(acc[i][1]+bc[1]),
                                         (float)(acc[i][2]+bc[2]), (float)(acc[i][3]+bc[3]));
    }
}

// ---------------- VQ: bf16 MFMA prefilter + canonical-fp32-quantized argmin on near-ties ----
// Prefilter error sigma ~3e-7 vs score spread ~2e-4; tol 1e-5 (~24 sigma); near-ties
// rescored canonically.  [LOCKED numerics on the rescore path]
__global__ __launch_bounds__(512) void vq_kernel(
    const float* __restrict__ F, const float* __restrict__ CB,
    const unsigned short* __restrict__ CBH,
    const float* __restrict__ cnorm, float* __restrict__ idx_out,
    float* __restrict__ qout, float* __restrict__ msd_acc)
{
    __shared__ unsigned short a_bf[64*256];   // 32 KB, swizzled bf16 F-tile
    __shared__ unsigned short b_bf[128*256];  // 64 KB, swizzled bf16 CB-chunk
    __shared__ float cn_s[128];
    __shared__ float red_v[64*64];            // top-2 per (row, entry); reused for msd reduce
    __shared__ int   red_i[64*64];
    __shared__ int   bests[64];
    __shared__ int   cand[64][12];
    __shared__ int   ccnt[64];
    const int tid = threadIdx.x;
    const int m0 = blockIdx.x * 64;

    // ---- stage A once: F[m0..m0+64) x 256 -> bf16, swizzled ----
    #pragma unroll
    for (int u = 0; u < 4; u++) {
        int e = tid + u*512;                 // < 2048
        int row = e >> 5, c = e & 31;
        const float* src = &F[(size_t)(m0+row)*NDCB + c*8];
        float4 f0 = *(const float4*)src;
        float4 f1 = *(const float4*)(src+4);
        u16x8 p;
        p[0]=f2bf(f0.x); p[1]=f2bf(f0.y); p[2]=f2bf(f0.z); p[3]=f2bf(f0.w);
        p[4]=f2bf(f1.x); p[5]=f2bf(f1.y); p[6]=f2bf(f1.z); p[7]=f2bf(f1.w);
        *(u16x8*)((char*)a_bf + row*512 + ((c*16) ^ ((row&7)<<4))) = p;
    }

    // wave w: rows 16*(w&3), cols 64*(w>>2) of each 64x128 chunk
    const int w = tid >> 6, lane = tid & 63;
    const int l15 = lane & 15, kg = lane >> 4;
    const int rbase = (w & 3) << 4, cbase = (w >> 2) << 6;
    const char* aP = (const char*)a_bf + (size_t)(rbase + l15)*512;
    const char* bP = (const char*)b_bf + (size_t)(cbase + l15)*512;
    const int swz = (lane & 7) << 4;

    float mv1[4], mv2[4]; int mi1[4], mi2[4];
    #pragma unroll
    for (int i = 0; i < 4; i++) { mv1[i]=3.0e38f; mv2[i]=3.0e38f; mi1[i]=0x7fffffff; mi2[i]=0x7fffffff; }

    for (int n0 = 0; n0 < NKCB; n0 += 128) {
        __syncthreads();                      // previous chunk's MFMA reads done
        #pragma unroll
        for (int u = 0; u < 8; u++) {
            int e = tid + u*512;              // < 4096
            int row = e >> 5, c = e & 31;
            u16x8 v = *(const u16x8*)&CBH[(size_t)(n0+row)*NDCB + c*8];
            *(u16x8*)((char*)b_bf + row*512 + ((c*16) ^ ((row&7)<<4))) = v;
        }
        if (tid < 128) cn_s[tid] = cnorm[n0 + tid];
        __syncthreads();
        f32x4 acc[4] = {{0.f,0.f,0.f,0.f},{0.f,0.f,0.f,0.f},{0.f,0.f,0.f,0.f},{0.f,0.f,0.f,0.f}};
        #pragma unroll
        for (int kt = 0; kt < 8; kt++) {
            const int ko = (kt*64 + kg*16) ^ swz;
            bf16x8 av = *(const bf16x8*)(aP + ko);
            #pragma unroll
            for (int f = 0; f < 4; f++) {
                bf16x8 bv = *(const bf16x8*)(bP + f*8192 + ko);
                acc[f] = __builtin_amdgcn_mfma_f32_16x16x32_bf16(av, bv, acc[f], 0, 0, 0);
            }
        }
        // epilogue: s = cn - 2*dot ; per-lane top-2.  C layout: col=lane&15, row=(lane>>4)*4+reg.
        #pragma unroll
        for (int f = 0; f < 4; f++) {
            const int col = n0 + cbase + f*16 + l15;
            const float cnv = cn_s[cbase + f*16 + l15];
            #pragma unroll
            for (int i = 0; i < 4; i++) {
                float s = fmaf(-2.0f, acc[f][i], cnv);
                if (s < mv1[i]) { mv2[i]=mv1[i]; mi2[i]=mi1[i]; mv1[i]=s; mi1[i]=col; }
                else if (s < mv2[i]) { mv2[i]=s; mi2[i]=col; }
            }
        }
    }
    #pragma unroll
    for (int i = 0; i < 4; i++) {
        const int row = rbase + kg*4 + i;
        const int eb  = (w>>2)*32 + l15*2;
        red_v[row*64 + eb]   = mv1[i]; red_i[row*64 + eb]   = mi1[i];
        red_v[row*64 + eb+1] = mv2[i]; red_i[row*64 + eb+1] = mi2[i];
    }
    __syncthreads();
    if (tid < 64) {
        float bv = 3.0e38f; int bi = 0x7fffffff;
        for (int e = 0; e < 64; e++) {
            float v = red_v[tid*64 + e]; int ii = red_i[tid*64 + e];
            if (v < bv || (v == bv && ii < bi)) { bv = v; bi = ii; }
        }
        int cnt = 0;
        for (int e = 0; e < 64; e++) {
            if (red_v[tid*64 + e] < bv + 1.0e-5f) {
                if (cnt < 12) cand[tid][cnt] = red_i[tid*64 + e];
                cnt++;
            }
        }
        bests[tid] = bi;
        ccnt[tid] = (cnt > 12) ? 12 : cnt;
    }
    __syncthreads();
    // Canonical fp32-quantized rescore of near-tie rows (one wave per row, round-robin).
    {
        const int wid = tid >> 6, lane2 = tid & 63;
        for (int r = wid; r < 64; r += 8) {
            const int nc = ccnt[r];
            if (nc < 2) continue;
            double sf = 0.0;
            #pragma unroll
            for (int u = 0; u < 4; u++) {
                double fv = (double)F[(size_t)(m0+r)*NDCB + lane2*4 + u];
                sf = fma(fv, fv, sf);
            }
            #pragma unroll
            for (int off = 32; off > 0; off >>= 1) sf += __shfl_down(sf, off);
            const float sf32 = (float)sf;          // valid on lane 0
            float bd2 = 0.0f; int bidx = 0x7fffffff;
            for (int c = 0; c < nc; c++) {
                const int k = cand[r][c];
                double g = 0.0;
                #pragma unroll
                for (int u = 0; u < 4; u++) {
                    double cv = (double)CB[(size_t)k*NDCB + lane2*4 + u];
                    double fv = (double)F[(size_t)(m0+r)*NDCB + lane2*4 + u];
                    g = fma(cv, fv, g);
                }
                #pragma unroll
                for (int off = 32; off > 0; off >>= 1) g += __shfl_down(g, off);
                if (lane2 == 0) {
                    const float G32 = (float)g;
                    const float t  = sf32 - 2.0f*G32;
                    const float d2 = t + cnorm[k];
                    if (c == 0 || d2 < bd2 || (d2 == bd2 && k < bidx)) { bd2 = d2; bidx = k; }
                }
            }
            if (lane2 == 0) bests[r] = bidx;
        }
    }
    __syncthreads();
    if (tid < 64) idx_out[m0 + tid] = (float)bests[tid];
    float lsum = 0.0f;
    #pragma unroll
    for (int s = 0; s < 8; s++) {
        int e = tid + s*512;
        int row = e >> 6, kqe = (e & 63) << 2;
        float4 q = *(const float4*)&CB[(size_t)bests[row]*NDCB + kqe];
        float4 f = *(const float4*)&F[(size_t)(m0+row)*NDCB + kqe];
        float dx=f.x-q.x, dy=f.y-q.y, dz=f.z-q.z, dw=f.w-q.w;
        lsum += dx*dx + dy*dy + dz*dz + dw*dw;
        *(float4*)&qout[(size_t)(m0+row)*NDCB + kqe] = q;
    }
    red_v[tid] = lsum;
    __syncthreads();
    for (int off = 256; off > 0; off >>= 1) {
        if (tid < off) red_v[tid] += red_v[tid + off];
        __syncthreads();
    }
    if (tid == 0) atomicAdd(msd_acc, red_v[0]);
}

// ---------------- xproj: f16 MFMA GEMM (feeds GRU/context_loss, 2% threshold) ----------------
__global__ __launch_bounds__(512) void xproj_mfma_kernel(
    const float* __restrict__ Q, const unsigned short* __restrict__ WIHH,
    const float* __restrict__ bias, float* __restrict__ C)
{
    __shared__ unsigned short a_h[64*256];    // 32 KB, swizzled f16 (q * 8192)
    __shared__ unsigned short b_h[128*256];   // 64 KB, swizzled f16 wih chunk
    const int tid = threadIdx.x;
    const int m0 = blockIdx.x * 64;

    #pragma unroll
    for (int u = 0; u < 4; u++) {
        int e = tid + u*512;                 // < 2048
        int row = e >> 5, c = e & 31;
        const float* src = &Q[(size_t)(m0+row)*NDCB + c*8];
        float4 f0 = *(const float4*)src;
        float4 f1 = *(const float4*)(src+4);
        f16x8 p;
        p[0]=(_Float16)(f0.x*8192.0f); p[1]=(_Float16)(f0.y*8192.0f);
        p[2]=(_Float16)(f0.z*8192.0f); p[3]=(_Float16)(f0.w*8192.0f);
        p[4]=(_Float16)(f1.x*8192.0f); p[5]=(_Float16)(f1.y*8192.0f);
        p[6]=(_Float16)(f1.z*8192.0f); p[7]=(_Float16)(f1.w*8192.0f);
        *(f16x8*)((char*)a_h + row*512 + ((c*16) ^ ((row&7)<<4))) = p;
    }

    const int w = tid >> 6, lane = tid & 63;
    const int l15 = lane & 15, kg = lane >> 4;
    const int rbase = (w & 3) << 4, cbase = (w >> 2) << 6;
    const char* aP = (const char*)a_h + (size_t)(rbase + l15)*512;
    const char* bP = (const char*)b_h + (size_t)(cbase + l15)*512;
    const int swz = (lane & 7) << 4;

    for (int n0 = 0; n0 < 768; n0 += 128) {
        __syncthreads();
        #pragma unroll
        for (int u = 0; u < 8; u++) {
            int e = tid + u*512;              // < 4096
            int row = e >> 5, c = e & 31;
            u16x8 v = *(const u16x8*)&WIHH[(size_t)(n0+row)*NDCB + c*8];
            *(u16x8*)((char*)b_h + row*512 + ((c*16) ^ ((row&7)<<4))) = v;
        }
        __syncthreads();
        f32x4 acc[4] = {{0.f,0.f,0.f,0.f},{0.f,0.f,0.f,0.f},{0.f,0.f,0.f,0.f},{0.f,0.f,0.f,0.f}};
        #pragma unroll
        for (int kt = 0; kt < 8; kt++) {
            const int ko = (kt*64 + kg*16) ^ swz;
            f16x8 av = *(const f16x8*)(aP + ko);
            #pragma unroll
            for (int f = 0; f < 4; f++) {
                f16x8 bv = *(const f16x8*)(bP + f*8192 + ko);
                acc[f] = __builtin_amdgcn_mfma_f32_16x16x32_f16(av, bv, acc[f], 0, 0, 0);
            }
        }
        // C layout: col=lane&15, row=(lane>>4)*4+reg
        #pragma unroll
        for (int f = 0; f < 4; f++) {
            const int col = n0 + cbase + f*16 + l15;
            const float bv = bias[col];
            #pragma unroll
            for (int i = 0; i < 4; i++) {
                const int row = m0 + rbase + kg*4 + i;
                C[(size_t)row*768 + col] = fmaf(acc[f][i], 1.0f/8192.0f, bv);
            }
        }
    }
}

// ---------------- GRU scan: shared body, three occupancy shells ------------------------------
// Needs ~220 VGPR (192 half2 weights + working set).  The allocator has pegged the budget at
// the 4-waves/EU tier (128) in every config tried so far; variants below probe the two
// remaining budget knobs.  Runtime dispatch picks the first spill-free compile.
__device__ __forceinline__ void gru_body(
    const float* __restrict__ XP, const float* __restrict__ WHH,
    const float* __restrict__ bhh, const float* __restrict__ F,
    float* __restrict__ ctx_acc)
{
    __shared__ float part[3][2][256];
    __shared__ uint4 hpk[2][32];      // double-buffered f16x2-packed h[256]
    __shared__ float red[256];
    const int tid = threadIdx.x;
    const int b = blockIdx.x;
    const int j = tid & 255;
    const int q = tid >> 8;           // 0..1
    half2_t wr[64], wz[64], wn[64];
    {
        const float* rp = WHH + (size_t)j*256 + q*128;
        #pragma unroll
        for (int k = 0; k < 32; k++) {
            float4 vr = *(const float4*)(rp + 4*k);
            float4 vz = *(const float4*)(rp + 65536 + 4*k);
            float4 vn = *(const float4*)(rp + 131072 + 4*k);
            wr[2*k+0] = (half2_t){(_Float16)vr.x, (_Float16)vr.y};
            wr[2*k+1] = (half2_t){(_Float16)vr.z, (_Float16)vr.w};
            wz[2*k+0] = (half2_t){(_Float16)vz.x, (_Float16)vz.y};
            wz[2*k+1] = (half2_t){(_Float16)vz.z, (_Float16)vz.w};
            wn[2*k+0] = (half2_t){(_Float16)vn.x, (_Float16)vn.y};
            wn[2*k+1] = (half2_t){(_Float16)vn.z, (_Float16)vn.w};
        }
    }
    if (tid < 64) hpk[tid >> 5][tid & 31] = make_uint4(0u, 0u, 0u, 0u);
    const float bb0 = bhh[j], bb1 = bhh[256+j], bb2 = bhh[512+j];
    const float* xpb = XP + (size_t)b*NT*768;
    const float* fb  = F  + (size_t)b*NT*NDCB;
    float hprev = 0.0f, lsum = 0.0f;
    __syncthreads();
    int cur = 0;
    for (int t = 0; t < NT-1; t++) {
        float xr = 0.f, xz = 0.f, xn = 0.f, fv = 0.f;
        if (tid < 256) {               // waves 0..3, wave-uniform branch
            const float* xp = xpb + (size_t)t*768;
            xr = xp[j]; xz = xp[256+j]; xn = xp[512+j];
            fv = fb[(size_t)(t+1)*NDCB + j];
        }
        float a0=0.f, c0=0.f, a1=0.f, c1=0.f, a2=0.f, c2=0.f;
        #pragma unroll
        for (int kk = 0; kk < 16; kk++) {
            uint4 hp = hpk[cur][q*16 + kk];           // wave-uniform -> LDS broadcast
            half2_t h0 = __builtin_bit_cast(half2_t, hp.x);
            half2_t h1 = __builtin_bit_cast(half2_t, hp.y);
            half2_t h2 = __builtin_bit_cast(half2_t, hp.z);
            half2_t h3 = __builtin_bit_cast(half2_t, hp.w);
            a0 = dot2f(wr[4*kk+0], h0, a0); c0 = dot2f(wr[4*kk+1], h1, c0);
            a1 = dot2f(wz[4*kk+0], h0, a1); c1 = dot2f(wz[4*kk+1], h1, c1);
            a2 = dot2f(wn[4*kk+0], h0, a2); c2 = dot2f(wn[4*kk+1], h1, c2);
            a0 = dot2f(wr[4*kk+2], h2, a0); c0 = dot2f(wr[4*kk+3], h3, c0);
            a1 = dot2f(wz[4*kk+2], h2, a1); c1 = dot2f(wz[4*kk+3], h3, c1);
            a2 = dot2f(wn[4*kk+2], h2, a2); c2 = dot2f(wn[4*kk+3], h3, c2);
        }
        part[0][q][j] = a0 + c0; part[1][q][j] = a1 + c1; part[2][q][j] = a2 + c2;
        __syncthreads();
        if (tid < 256) {
            float ghr = part[0][0][j] + part[0][1][j] + bb0;
            float ghz = part[1][0][j] + part[1][1][j] + bb1;
            float ghn = part[2][0][j] + part[2][1][j] + bb2;
            float r = 1.0f/(1.0f + __expf(-(xr + ghr)));
            float z = 1.0f/(1.0f + __expf(-(xz + ghz)));
            float v = fmaf(r, ghn, xn);
            v = fminf(fmaxf(v, -12.0f), 12.0f);          // clamped fast tanh
            float ev = __expf(-2.0f*v);
            float n = (1.0f - ev)/(1.0f + ev);
            float hnew = (1.0f - z)*n + z*hprev;
            float d = hnew - fv;
            lsum = fmaf(d, d, lsum);
            float nb = __shfl_down(hnew, 1);             // neighbor j+1, same wave
            if (!(j & 1)) {
                half2_t p; p[0] = (_Float16)hnew; p[1] = (_Float16)nb;
                ((unsigned int*)&hpk[cur ^ 1][0])[j >> 1] = __builtin_bit_cast(unsigned int, p);
            }
            hprev = hnew;
        }
        __syncthreads();
        cur ^= 1;
    }
    if (tid < 256) red[j] = lsum;
    __syncthreads();
    for (int off = 128; off > 0; off >>= 1) {
        if (tid < off) red[tid] += red[tid + off];
        __syncthreads();
    }
    if (tid == 0) atomicAdd(ctx_acc, red[0]);
}

// Variant A: attribute-only occupancy pin (no __launch_bounds__ macro at all).
__global__ __attribute__((amdgpu_flat_work_group_size(512, 512), amdgpu_waves_per_eu(2, 2)))
void gru_a(const float* __restrict__ XP, const float* __restrict__ WHH,
           const float* __restrict__ bhh, const float* __restrict__ F,
           float* __restrict__ ctx_acc)
{ gru_body(XP, WHH, bhh, F, ctx_acc); }

// Variant B: __launch_bounds__ 2nd arg = 2 (HIP-doc semantics: min waves/EU -> 256-VGPR budget).
__global__ __launch_bounds__(512, 2)
void gru_b(const float* __restrict__ XP, const float* __restrict__ WHH,
           const float* __restrict__ bhh, const float* __restrict__ F,
           float* __restrict__ ctx_acc)
{ gru_body(XP, WHH, bhh, F, ctx_acc); }

// Variant C: known-working fallback (R3 behavior: 128 VGPR + spill replay, ~655 us).
__global__ __launch_bounds__(512)
void gru_c(const float* __restrict__ XP, const float* __restrict__ WHH,
           const float* __restrict__ bhh, const float* __restrict__ F,
           float* __restrict__ ctx_acc)
{ gru_body(XP, WHH, bhh, F, ctx_acc); }

// ---------------- small prep kernels ----------------
__global__ __launch_bounds__(256) void prep_kernel(
    const float* __restrict__ conv_w, float* __restrict__ w3,
    const float* __restrict__ wih, unsigned short* __restrict__ wihh,
    float* __restrict__ accv)
{
    int e = blockIdx.x*256 + threadIdx.x;     // < 196608
    if (e == 0) { accv[0] = 0.0f; accv[1] = 0.0f; }
    {   // w3[k][c][i] = conv_w[c][i][k]
        int k = e >> 16;
        int r = e & 65535;
        int c = r >> 8, i = r & 255;
        w3[e] = conv_w[(size_t)c*768 + i*3 + k];
    }
    {   // wih f32 -> f16 bits (768*256 = 196608 elements, exactly this grid)
        _Float16 h = (_Float16)wih[e];
        wihh[e] = __builtin_bit_cast(unsigned short, h);
    }
}

// codebook fp32 -> bf16 (RNE), for the MFMA prefilter
__global__ __launch_bounds__(256) void cb2bf_kernel(
    const float* __restrict__ cb, unsigned short* __restrict__ cbh)
{
    int e = (blockIdx.x*256 + threadIdx.x) * 4;   // 2,097,152 elems / 4
    float4 v = *(const float4*)&cb[e];
    unsigned short p0 = f2bf(v.x), p1 = f2bf(v.y), p2 = f2bf(v.z), p3 = f2bf(v.w);
    unsigned long long pk = (unsigned long long)p0 | ((unsigned long long)p1 << 16)
                          | ((unsigned long long)p2 << 32) | ((unsigned long long)p3 << 48);
    *(unsigned long long*)&cbh[e] = pk;
}

// s_c = fl32(exact sum c^2) via fp64   [LOCKED numerics]
__global__ __launch_bounds__(64) void cnorm_kernel(
    const float* __restrict__ CB, float* __restrict__ cn)
{
    const int k = blockIdx.x;
    const int lane = threadIdx.x;
    float4 v = *(const float4*)&CB[(size_t)k*NDCB + lane*4];
    double s = (double)v.x*(double)v.x + (double)v.y*(double)v.y
             + (double)v.z*(double)v.z + (double)v.w*(double)v.w;
    #pragma unroll
    for (int off = 32; off > 0; off >>= 1) s += __shfl_down(s, off);
    if (lane == 0) cn[k] = (float)s;
}

__global__ void finalize_kernel(const float* __restrict__ acc, float* __restrict__ out)
{
    if (threadIdx.x == 0) {
        float msd = acc[0] * (1.0f/4194304.0f);   // mean over 32*512*256
        float ctx = acc[1] * (1.0f/4184064.0f);   // mean over 32*511*256
        out[0] = msd;                 // commitment_loss
        out[1] = msd;                 // codebook_loss (same forward value)
        out[2] = ctx;                 // context_loss
        out[3] = 1.25f*msd + 0.1f*ctx; // vq_loss
    }
}

extern "C" void kernel_launch(void* const* d_in, const int* in_sizes, int n_in,
                              void* d_out, int out_size, void* d_ws, size_t ws_size,
                              hipStream_t stream) {
    const float* x      = (const float*)d_in[0];
    const float* w1     = (const float*)d_in[1];
    const float* b1     = (const float*)d_in[2];
    const float* w2     = (const float*)d_in[3];
    const float* b2     = (const float*)d_in[4];
    const float* conv_w = (const float*)d_in[5];
    const float* conv_b = (const float*)d_in[6];
    const float* cb     = (const float*)d_in[7];
    const float* wih    = (const float*)d_in[8];
    const float* whh    = (const float*)d_in[9];
    const float* bih    = (const float*)d_in[10];
    const float* bhh    = (const float*)d_in[11];
    float* out = (float*)d_out;

    // workspace layout (regions re-used once dead):
    //   [0,        16.7M)  feat  (fp32)          conv -> gru
    //   [16.7M,    50.3M)  h1    (fp32)          gemm1 -> gemm2
    //   [16.7M,    67.1M)  xproj (fp32, 50.3MB)  gemm3 -> gru   (overlays dead h1+h2)
    //   [50.3M,    67.1M)  h2    (fp32)          gemm2 -> conv
    //   [50.3M,    54.5M)  cbh   (bf16, 4MB)     cb2bf -> vq    (overlays dead h2)
    //   [67.1M, ...]       cn / w3 / wihh / accv
    char* ws = (char*)d_ws;
    float*  feat   = (float*)(ws + 0);
    float*  h1     = (float*)(ws + 16777216);
    float*  xproj  = (float*)(ws + 16777216);
    float*  h2     = (float*)(ws + 50331648);
    unsigned short* cbh = (unsigned short*)(ws + 50331648);
    float*  cn     = (float*)(ws + 67108864);
    float*  w3     = (float*)(ws + 67141632);
    unsigned short* wihh = (unsigned short*)(ws + 67928064);   // 393216 B (old wht slot)
    float*  accv   = (float*)(ws + 68714496);

    float* idx_out = out;                   // 16384 indices (as float)
    float* qout    = out + 16384;           // 4,194,304 quantized
    float* louts   = out + 16384 + 4194304; // 4 scalars

    // Pick the first spill-free GRU shell (pure host-side query; cached; capture-safe).
    static int gsel = -1;
    if (gsel < 0) {
        hipFuncAttributes fa;
        gsel = 2;
        if (hipFuncGetAttributes(&fa, reinterpret_cast<const void*>(gru_a)) == hipSuccess
            && fa.localSizeBytes == 0 && fa.numRegs >= 193) gsel = 0;
        else if (hipFuncGetAttributes(&fa, reinterpret_cast<const void*>(gru_b)) == hipSuccess
            && fa.localSizeBytes == 0 && fa.numRegs >= 193) gsel = 1;
    }

    prep_kernel<<<768, 256, 0, stream>>>(conv_w, w3, wih, wihh, accv);
    cnorm_kernel<<<NKCB, 64, 0, stream>>>(cb, cn);
    gemm_nt_f64_kernel<true ><<<dim3(NHMID/64, NROWS/64), 256, 0, stream>>>(x,  w1, b1, h1, NROWS, NHMID, NDIN);
    gemm_nt_f64_kernel<true ><<<dim3(NDCB/64,  NROWS/64), 256, 0, stream>>>(h1, w2, b2, h2, NROWS, NDCB, NHMID);
    conv3_f64_kernel<<<dim3(NDCB/64, NROWS/64), 256, 0, stream>>>(h2, w3, conv_b, feat);
    cb2bf_kernel<<<2048, 256, 0, stream>>>(cb, cbh);   // after conv3: overlays dead h2
    vq_kernel<<<NROWS/64, 512, 0, stream>>>(feat, cb, cbh, cn, idx_out, qout, accv);
    xproj_mfma_kernel<<<NROWS/64, 512, 0, stream>>>(qout, wihh, bih, xproj);
    if (gsel == 0)      gru_a<<<NB, 512, 0, stream>>>(xproj, whh, bhh, feat, accv + 1);
    else if (gsel == 1) gru_b<<<NB, 512, 0, stream>>>(xproj, whh, bhh, feat, accv + 1);
    else                gru_c<<<NB, 512, 0, stream>>>(xproj, whh, bhh, feat, accv + 1);
    finalize_kernel<<<1, 64, 0, stream>>>(accv, louts);
}

// Round 5
// 1761.937 us; speedup vs baseline: 3.9206x; 1.0101x over previous
//
#include <hip/hip_runtime.h>
#include <math.h>

#define NB 32
#define NT 512
#define NDIN 1024
#define NDCB 256
#define NKCB 8192
#define NHMID 512
#define NROWS (NB*NT)   // 16384

typedef _Float16 half2_t __attribute__((ext_vector_type(2)));
typedef _Float16 f16x8 __attribute__((ext_vector_type(8)));
typedef __attribute__((ext_vector_type(8))) short bf16x8;
typedef __attribute__((ext_vector_type(8))) unsigned short u16x8;
typedef __attribute__((ext_vector_type(4))) float f32x4;

__device__ __forceinline__ unsigned short f2bf(float x) {
    unsigned int u = __float_as_uint(x);
    return (unsigned short)((u + 0x7fffu + ((u >> 16) & 1u)) >> 16);   // RNE
}

#if __has_builtin(__builtin_amdgcn_fdot2)
__device__ __forceinline__ float dot2f(half2_t a, half2_t b, float c) {
    return __builtin_amdgcn_fdot2(a, b, c, false);
}
#else
__device__ __forceinline__ float dot2f(half2_t a, half2_t b, float c) {
    return fmaf((float)a[0], (float)b[0], fmaf((float)a[1], (float)b[1], c));
}
#endif

// ---------------- fp64-accumulate tiled GEMM: C = act(A(MxK) * B(NxK)^T + bias) ----------------
// fp32 in/out, fp64 accumulation: output = fl(exact), the canonical fp32 result.  [LOCKED numerics]
template<bool RELU>
__global__ __launch_bounds__(256) void gemm_nt_f64_kernel(
    const float* __restrict__ A, const float* __restrict__ Bm,
    const float* __restrict__ bias, float* __restrict__ C,
    int M, int N, int K)
{
    __shared__ double a_s[16*64];
    __shared__ double b_s[16*64];
    const int tid = threadIdx.x;
    const int bn0 = blockIdx.x * 64;
    const int bm0 = blockIdx.y * 64;
    const int lr = tid >> 2;          // 0..63
    const int kq = (tid & 3) << 2;    // 0,4,8,12
    const int tx = tid & 15, ty = tid >> 4;
    double acc[4][4] = {};
    const float* Ap = A + (size_t)(bm0 + lr) * K + kq;
    const float* Bp = Bm + (size_t)(bn0 + lr) * K + kq;
    for (int kt = 0; kt < K; kt += 16) {
        float4 a = *(const float4*)(Ap + kt);
        float4 b = *(const float4*)(Bp + kt);
        __syncthreads();
        a_s[(kq+0)*64+lr] = (double)a.x; a_s[(kq+1)*64+lr] = (double)a.y;
        a_s[(kq+2)*64+lr] = (double)a.z; a_s[(kq+3)*64+lr] = (double)a.w;
        b_s[(kq+0)*64+lr] = (double)b.x; b_s[(kq+1)*64+lr] = (double)b.y;
        b_s[(kq+2)*64+lr] = (double)b.z; b_s[(kq+3)*64+lr] = (double)b.w;
        __syncthreads();
        #pragma unroll
        for (int kk = 0; kk < 16; kk++) {
            double aa[4], bb[4];
            #pragma unroll
            for (int u = 0; u < 4; u++) { aa[u] = a_s[kk*64 + ty*4 + u]; bb[u] = b_s[kk*64 + tx*4 + u]; }
            #pragma unroll
            for (int i = 0; i < 4; i++)
                #pragma unroll
                for (int j = 0; j < 4; j++)
                    acc[i][j] = fma(aa[i], bb[j], acc[i][j]);
        }
    }
    const float4 b4 = *(const float4*)&bias[bn0 + tx*4];
    const double bc[4] = {(double)b4.x, (double)b4.y, (double)b4.z, (double)b4.w};
    #pragma unroll
    for (int i = 0; i < 4; i++) {
        float o[4];
        #pragma unroll
        for (int j = 0; j < 4; j++) {
            double v = acc[i][j] + bc[j];
            if (RELU) v = fmax(v, 0.0);
            o[j] = (float)v;
        }
        *(float4*)&C[(size_t)(bm0 + ty*4 + i)*N + bn0 + tx*4] =
            make_float4(o[0], o[1], o[2], o[3]);
    }
}

// ---------------- conv1d k=3 SAME, fp64 accumulation ----------------  [LOCKED numerics]
__global__ __launch_bounds__(256) void conv3_f64_kernel(
    const float* __restrict__ H2, const float* __restrict__ W3,
    const float* __restrict__ bias, float* __restrict__ F)
{
    __shared__ double a_s[16*68];       // [k][local row], local l <-> global bm0-1+l
    __shared__ double b_s[3][16*64];
    const int tid = threadIdx.x;
    const int bn0 = blockIdx.x * 64;
    const int bm0 = blockIdx.y * 64;
    const int lr = tid >> 2;
    const int kq = (tid & 3) << 2;
    const int tx = tid & 15, ty = tid >> 4;
    const int tmod = bm0 & (NT-1);
    const bool has_top = (tmod != 0);
    const bool has_bot = (tmod + 64 < NT);
    double acc[4][4] = {};
    for (int kt = 0; kt < NDCB; kt += 16) {
        float4 a = make_float4(0.f,0.f,0.f,0.f);
        if (lr >= 1 || has_top)
            a = *(const float4*)&H2[(size_t)(bm0 - 1 + lr)*NDCB + kt + kq];
        float4 e = make_float4(0.f,0.f,0.f,0.f);
        int l2 = 0, kq2 = 0;
        if (tid < 8) {
            l2 = 64 + (tid >> 2); kq2 = (tid & 3) << 2;
            if (l2 == 64 || has_bot)
                e = *(const float4*)&H2[(size_t)(bm0 - 1 + l2)*NDCB + kt + kq2];
        }
        float4 w[3];
        #pragma unroll
        for (int s = 0; s < 3; s++)
            w[s] = *(const float4*)&W3[(size_t)s*65536 + (size_t)(bn0 + lr)*NDCB + kt + kq];
        __syncthreads();
        a_s[(kq+0)*68+lr]=(double)a.x; a_s[(kq+1)*68+lr]=(double)a.y;
        a_s[(kq+2)*68+lr]=(double)a.z; a_s[(kq+3)*68+lr]=(double)a.w;
        if (tid < 8) {
            a_s[(kq2+0)*68+l2]=(double)e.x; a_s[(kq2+1)*68+l2]=(double)e.y;
            a_s[(kq2+2)*68+l2]=(double)e.z; a_s[(kq2+3)*68+l2]=(double)e.w;
        }
        #pragma unroll
        for (int s = 0; s < 3; s++) {
            b_s[s][(kq+0)*64+lr]=(double)w[s].x; b_s[s][(kq+1)*64+lr]=(double)w[s].y;
            b_s[s][(kq+2)*64+lr]=(double)w[s].z; b_s[s][(kq+3)*64+lr]=(double)w[s].w;
        }
        __syncthreads();
        #pragma unroll
        for (int kk = 0; kk < 16; kk++) {
            double aa[6];
            #pragma unroll
            for (int u = 0; u < 6; u++) aa[u] = a_s[kk*68 + ty*4 + u];
            #pragma unroll
            for (int s = 0; s < 3; s++) {
                double bb[4];
                #pragma unroll
                for (int u = 0; u < 4; u++) bb[u] = b_s[s][kk*64 + tx*4 + u];
                #pragma unroll
                for (int i = 0; i < 4; i++)
                    #pragma unroll
                    for (int j = 0; j < 4; j++)
                        acc[i][j] = fma(aa[i+s], bb[j], acc[i][j]);
            }
        }
    }
    const float4 b4 = *(const float4*)&bias[bn0 + tx*4];
    const double bc[4] = {(double)b4.x, (double)b4.y, (double)b4.z, (double)b4.w};
    #pragma unroll
    for (int i = 0; i < 4; i++) {
        const size_t base = (size_t)(bm0 + ty*4 + i)*NDCB + bn0 + tx*4;
        *(float4*)&F[base] = make_float4((float)(acc[i][0]+bc[0]), (float)(acc[i][1]+bc[1]),
                                         (float)(acc[i][2]+bc[2]), (float)(acc[i][3]+bc[3]));
    }
}

// ---------------- VQ: bf16 MFMA prefilter + canonical-fp32-quantized argmin on near-ties ----
// Prefilter error sigma ~3e-7 vs score spread ~2e-4; tol 1e-5 (~24 sigma); near-ties
// rescored canonically.  [LOCKED numerics on the rescore path]
__global__ __launch_bounds__(512) void vq_kernel(
    const float* __restrict__ F, const float* __restrict__ CB,
    const unsigned short* __restrict__ CBH,
    const float* __restrict__ cnorm, float* __restrict__ idx_out,
    float* __restrict__ qout, float* __restrict__ msd_acc)
{
    __shared__ unsigned short a_bf[64*256];   // 32 KB, swizzled bf16 F-tile
    __shared__ unsigned short b_bf[128*256];  // 64 KB, swizzled bf16 CB-chunk
    __shared__ float cn_s[128];
    __shared__ float red_v[64*64];            // top-2 per (row, entry); reused for msd reduce
    __shared__ int   red_i[64*64];
    __shared__ int   bests[64];
    __shared__ int   cand[64][12];
    __shared__ int   ccnt[64];
    const int tid = threadIdx.x;
    const int m0 = blockIdx.x * 64;

    // ---- stage A once: F[m0..m0+64) x 256 -> bf16, swizzled ----
    #pragma unroll
    for (int u = 0; u < 4; u++) {
        int e = tid + u*512;                 // < 2048
        int row = e >> 5, c = e & 31;
        const float* src = &F[(size_t)(m0+row)*NDCB + c*8];
        float4 f0 = *(const float4*)src;
        float4 f1 = *(const float4*)(src+4);
        u16x8 p;
        p[0]=f2bf(f0.x); p[1]=f2bf(f0.y); p[2]=f2bf(f0.z); p[3]=f2bf(f0.w);
        p[4]=f2bf(f1.x); p[5]=f2bf(f1.y); p[6]=f2bf(f1.z); p[7]=f2bf(f1.w);
        *(u16x8*)((char*)a_bf + row*512 + ((c*16) ^ ((row&7)<<4))) = p;
    }

    // wave w: rows 16*(w&3), cols 64*(w>>2) of each 64x128 chunk
    const int w = tid >> 6, lane = tid & 63;
    const int l15 = lane & 15, kg = lane >> 4;
    const int rbase = (w & 3) << 4, cbase = (w >> 2) << 6;
    const char* aP = (const char*)a_bf + (size_t)(rbase + l15)*512;
    const char* bP = (const char*)b_bf + (size_t)(cbase + l15)*512;
    const int swz = (lane & 7) << 4;

    float mv1[4], mv2[4]; int mi1[4], mi2[4];
    #pragma unroll
    for (int i = 0; i < 4; i++) { mv1[i]=3.0e38f; mv2[i]=3.0e38f; mi1[i]=0x7fffffff; mi2[i]=0x7fffffff; }

    for (int n0 = 0; n0 < NKCB; n0 += 128) {
        __syncthreads();                      // previous chunk's MFMA reads done
        #pragma unroll
        for (int u = 0; u < 8; u++) {
            int e = tid + u*512;              // < 4096
            int row = e >> 5, c = e & 31;
            u16x8 v = *(const u16x8*)&CBH[(size_t)(n0+row)*NDCB + c*8];
            *(u16x8*)((char*)b_bf + row*512 + ((c*16) ^ ((row&7)<<4))) = v;
        }
        if (tid < 128) cn_s[tid] = cnorm[n0 + tid];
        __syncthreads();
        f32x4 acc[4] = {{0.f,0.f,0.f,0.f},{0.f,0.f,0.f,0.f},{0.f,0.f,0.f,0.f},{0.f,0.f,0.f,0.f}};
        #pragma unroll
        for (int kt = 0; kt < 8; kt++) {
            const int ko = (kt*64 + kg*16) ^ swz;
            bf16x8 av = *(const bf16x8*)(aP + ko);
            #pragma unroll
            for (int f = 0; f < 4; f++) {
                bf16x8 bv = *(const bf16x8*)(bP + f*8192 + ko);
                acc[f] = __builtin_amdgcn_mfma_f32_16x16x32_bf16(av, bv, acc[f], 0, 0, 0);
            }
        }
        // epilogue: s = cn - 2*dot ; per-lane top-2.  C layout: col=lane&15, row=(lane>>4)*4+reg.
        #pragma unroll
        for (int f = 0; f < 4; f++) {
            const int col = n0 + cbase + f*16 + l15;
            const float cnv = cn_s[cbase + f*16 + l15];
            #pragma unroll
            for (int i = 0; i < 4; i++) {
                float s = fmaf(-2.0f, acc[f][i], cnv);
                if (s < mv1[i]) { mv2[i]=mv1[i]; mi2[i]=mi1[i]; mv1[i]=s; mi1[i]=col; }
                else if (s < mv2[i]) { mv2[i]=s; mi2[i]=col; }
            }
        }
    }
    #pragma unroll
    for (int i = 0; i < 4; i++) {
        const int row = rbase + kg*4 + i;
        const int eb  = (w>>2)*32 + l15*2;
        red_v[row*64 + eb]   = mv1[i]; red_i[row*64 + eb]   = mi1[i];
        red_v[row*64 + eb+1] = mv2[i]; red_i[row*64 + eb+1] = mi2[i];
    }
    __syncthreads();
    if (tid < 64) {
        float bv = 3.0e38f; int bi = 0x7fffffff;
        for (int e = 0; e < 64; e++) {
            float v = red_v[tid*64 + e]; int ii = red_i[tid*64 + e];
            if (v < bv || (v == bv && ii < bi)) { bv = v; bi = ii; }
        }
        int cnt = 0;
        for (int e = 0; e < 64; e++) {
            if (red_v[tid*64 + e] < bv + 1.0e-5f) {
                if (cnt < 12) cand[tid][cnt] = red_i[tid*64 + e];
                cnt++;
            }
        }
        bests[tid] = bi;
        ccnt[tid] = (cnt > 12) ? 12 : cnt;
    }
    __syncthreads();
    // Canonical fp32-quantized rescore of near-tie rows (one wave per row, round-robin).
    {
        const int wid = tid >> 6, lane2 = tid & 63;
        for (int r = wid; r < 64; r += 8) {
            const int nc = ccnt[r];
            if (nc < 2) continue;
            double sf = 0.0;
            #pragma unroll
            for (int u = 0; u < 4; u++) {
                double fv = (double)F[(size_t)(m0+r)*NDCB + lane2*4 + u];
                sf = fma(fv, fv, sf);
            }
            #pragma unroll
            for (int off = 32; off > 0; off >>= 1) sf += __shfl_down(sf, off);
            const float sf32 = (float)sf;          // valid on lane 0
            float bd2 = 0.0f; int bidx = 0x7fffffff;
            for (int c = 0; c < nc; c++) {
                const int k = cand[r][c];
                double g = 0.0;
                #pragma unroll
                for (int u = 0; u < 4; u++) {
                    double cv = (double)CB[(size_t)k*NDCB + lane2*4 + u];
                    double fv = (double)F[(size_t)(m0+r)*NDCB + lane2*4 + u];
                    g = fma(cv, fv, g);
                }
                #pragma unroll
                for (int off = 32; off > 0; off >>= 1) g += __shfl_down(g, off);
                if (lane2 == 0) {
                    const float G32 = (float)g;
                    const float t  = sf32 - 2.0f*G32;
                    const float d2 = t + cnorm[k];
                    if (c == 0 || d2 < bd2 || (d2 == bd2 && k < bidx)) { bd2 = d2; bidx = k; }
                }
            }
            if (lane2 == 0) bests[r] = bidx;
        }
    }
    __syncthreads();
    if (tid < 64) idx_out[m0 + tid] = (float)bests[tid];
    float lsum = 0.0f;
    #pragma unroll
    for (int s = 0; s < 8; s++) {
        int e = tid + s*512;
        int row = e >> 6, kqe = (e & 63) << 2;
        float4 q = *(const float4*)&CB[(size_t)bests[row]*NDCB + kqe];
        float4 f = *(const float4*)&F[(size_t)(m0+row)*NDCB + kqe];
        float dx=f.x-q.x, dy=f.y-q.y, dz=f.z-q.z, dw=f.w-q.w;
        lsum += dx*dx + dy*dy + dz*dz + dw*dw;
        *(float4*)&qout[(size_t)(m0+row)*NDCB + kqe] = q;
    }
    red_v[tid] = lsum;
    __syncthreads();
    for (int off = 256; off > 0; off >>= 1) {
        if (tid < off) red_v[tid] += red_v[tid + off];
        __syncthreads();
    }
    if (tid == 0) atomicAdd(msd_acc, red_v[0]);
}

// ---------------- xproj: f16 MFMA GEMM (feeds GRU/context_loss, 2% threshold) ----------------
__global__ __launch_bounds__(512) void xproj_mfma_kernel(
    const float* __restrict__ Q, const unsigned short* __restrict__ WIHH,
    const float* __restrict__ bias, float* __restrict__ C)
{
    __shared__ unsigned short a_h[64*256];    // 32 KB, swizzled f16 (q * 8192)
    __shared__ unsigned short b_h[128*256];   // 64 KB, swizzled f16 wih chunk
    const int tid = threadIdx.x;
    const int m0 = blockIdx.x * 64;

    #pragma unroll
    for (int u = 0; u < 4; u++) {
        int e = tid + u*512;                 // < 2048
        int row = e >> 5, c = e & 31;
        const float* src = &Q[(size_t)(m0+row)*NDCB + c*8];
        float4 f0 = *(const float4*)src;
        float4 f1 = *(const float4*)(src+4);
        f16x8 p;
        p[0]=(_Float16)(f0.x*8192.0f); p[1]=(_Float16)(f0.y*8192.0f);
        p[2]=(_Float16)(f0.z*8192.0f); p[3]=(_Float16)(f0.w*8192.0f);
        p[4]=(_Float16)(f1.x*8192.0f); p[5]=(_Float16)(f1.y*8192.0f);
        p[6]=(_Float16)(f1.z*8192.0f); p[7]=(_Float16)(f1.w*8192.0f);
        *(f16x8*)((char*)a_h + row*512 + ((c*16) ^ ((row&7)<<4))) = p;
    }

    const int w = tid >> 6, lane = tid & 63;
    const int l15 = lane & 15, kg = lane >> 4;
    const int rbase = (w & 3) << 4, cbase = (w >> 2) << 6;
    const char* aP = (const char*)a_h + (size_t)(rbase + l15)*512;
    const char* bP = (const char*)b_h + (size_t)(cbase + l15)*512;
    const int swz = (lane & 7) << 4;

    for (int n0 = 0; n0 < 768; n0 += 128) {
        __syncthreads();
        #pragma unroll
        for (int u = 0; u < 8; u++) {
            int e = tid + u*512;              // < 4096
            int row = e >> 5, c = e & 31;
            u16x8 v = *(const u16x8*)&WIHH[(size_t)(n0+row)*NDCB + c*8];
            *(u16x8*)((char*)b_h + row*512 + ((c*16) ^ ((row&7)<<4))) = v;
        }
        __syncthreads();
        f32x4 acc[4] = {{0.f,0.f,0.f,0.f},{0.f,0.f,0.f,0.f},{0.f,0.f,0.f,0.f},{0.f,0.f,0.f,0.f}};
        #pragma unroll
        for (int kt = 0; kt < 8; kt++) {
            const int ko = (kt*64 + kg*16) ^ swz;
            f16x8 av = *(const f16x8*)(aP + ko);
            #pragma unroll
            for (int f = 0; f < 4; f++) {
                f16x8 bv = *(const f16x8*)(bP + f*8192 + ko);
                acc[f] = __builtin_amdgcn_mfma_f32_16x16x32_f16(av, bv, acc[f], 0, 0, 0);
            }
        }
        // C layout: col=lane&15, row=(lane>>4)*4+reg
        #pragma unroll
        for (int f = 0; f < 4; f++) {
            const int col = n0 + cbase + f*16 + l15;
            const float bv = bias[col];
            #pragma unroll
            for (int i = 0; i < 4; i++) {
                const int row = m0 + rbase + kg*4 + i;
                C[(size_t)row*768 + col] = fmaf(acc[f][i], 1.0f/8192.0f, bv);
            }
        }
    }
}

// ---------------- GRU scan, 1024-thread layout: 96 half2 weight VGPRs fits the 128 tier ------
// The backend refuses >128 VGPR at any 512-thread config (R2-R4: 4 shells, all 128 + ~137-reg
// spill, 655us of L2 replay).  At 1024 threads one resident block = 16 waves = 4 waves/SIMD,
// whose HARDWARE cap is exactly 128 VGPR: per-thread need is 96 weight half2 + ~25 working,
// so the design fits the tier the allocator grants.  Thread (j=tid&255, q=tid>>8, q=0..3)
// owns gate rows {j,256+j,512+j} x i in [64q, 64q+64).
__device__ __forceinline__ void gru_body_1024(
    const float* __restrict__ XP, const float* __restrict__ WHH,
    const float* __restrict__ bhh, const float* __restrict__ F,
    float* __restrict__ ctx_acc)
{
    __shared__ float part[3][4][256];      // 12 KB
    __shared__ uint4 hpk[2][32];           // double-buffered f16x2-packed h[256]
    __shared__ float red[256];
    const int tid = threadIdx.x;
    const int b = blockIdx.x;
    const int j = tid & 255;
    const int q = tid >> 8;                // 0..3
    half2_t wr[32], wz[32], wn[32];        // 96 VGPRs
    {
        const float* rp = WHH + (size_t)j*256 + q*64;
        #pragma unroll
        for (int k = 0; k < 16; k++) {
            float4 vr = *(const float4*)(rp + 4*k);
            float4 vz = *(const float4*)(rp + 65536 + 4*k);
            float4 vn = *(const float4*)(rp + 131072 + 4*k);
            wr[2*k+0] = (half2_t){(_Float16)vr.x, (_Float16)vr.y};
            wr[2*k+1] = (half2_t){(_Float16)vr.z, (_Float16)vr.w};
            wz[2*k+0] = (half2_t){(_Float16)vz.x, (_Float16)vz.y};
            wz[2*k+1] = (half2_t){(_Float16)vz.z, (_Float16)vz.w};
            wn[2*k+0] = (half2_t){(_Float16)vn.x, (_Float16)vn.y};
            wn[2*k+1] = (half2_t){(_Float16)vn.z, (_Float16)vn.w};
        }
    }
    if (tid < 64) hpk[tid >> 5][tid & 31] = make_uint4(0u, 0u, 0u, 0u);
    const float bb0 = bhh[j], bb1 = bhh[256+j], bb2 = bhh[512+j];
    const float* xpb = XP + (size_t)b*NT*768;
    const float* fb  = F  + (size_t)b*NT*NDCB;
    float hprev = 0.0f, lsum = 0.0f;
    __syncthreads();
    int cur = 0;
    for (int t = 0; t < NT-1; t++) {
        // hoisted global loads (independent of h) — latency hidden behind phase A dot2s
        float xr = 0.f, xz = 0.f, xn = 0.f, fv = 0.f;
        if (tid < 256) {                   // waves 0..3, wave-uniform branch
            const float* xp = xpb + (size_t)t*768;
            xr = xp[j]; xz = xp[256+j]; xn = xp[512+j];
            fv = fb[(size_t)(t+1)*NDCB + j];
        }
        // phase A: 96 v_dot2_f32_f16 over this thread's 64-wide i-chunk, weights in regs
        float a0=0.f, c0=0.f, a1=0.f, c1=0.f, a2=0.f, c2=0.f;
        #pragma unroll
        for (int kk = 0; kk < 8; kk++) {
            uint4 hp = hpk[cur][q*8 + kk];            // wave-uniform -> LDS broadcast
            half2_t h0 = __builtin_bit_cast(half2_t, hp.x);
            half2_t h1 = __builtin_bit_cast(half2_t, hp.y);
            half2_t h2 = __builtin_bit_cast(half2_t, hp.z);
            half2_t h3 = __builtin_bit_cast(half2_t, hp.w);
            a0 = dot2f(wr[4*kk+0], h0, a0); c0 = dot2f(wr[4*kk+1], h1, c0);
            a1 = dot2f(wz[4*kk+0], h0, a1); c1 = dot2f(wz[4*kk+1], h1, c1);
            a2 = dot2f(wn[4*kk+0], h0, a2); c2 = dot2f(wn[4*kk+1], h1, c2);
            a0 = dot2f(wr[4*kk+2], h2, a0); c0 = dot2f(wr[4*kk+3], h3, c0);
            a1 = dot2f(wz[4*kk+2], h2, a1); c1 = dot2f(wz[4*kk+3], h3, c1);
            a2 = dot2f(wn[4*kk+2], h2, a2); c2 = dot2f(wn[4*kk+3], h3, c2);
        }
        part[0][q][j] = a0 + c0; part[1][q][j] = a1 + c1; part[2][q][j] = a2 + c2;
        __syncthreads();
        // phase B: gate nonlinearities + state update (waves 0..3 only)
        if (tid < 256) {
            float ghr = part[0][0][j] + part[0][1][j] + part[0][2][j] + part[0][3][j] + bb0;
            float ghz = part[1][0][j] + part[1][1][j] + part[1][2][j] + part[1][3][j] + bb1;
            float ghn = part[2][0][j] + part[2][1][j] + part[2][2][j] + part[2][3][j] + bb2;
            float r = 1.0f/(1.0f + __expf(-(xr + ghr)));
            float z = 1.0f/(1.0f + __expf(-(xz + ghz)));
            float v = fmaf(r, ghn, xn);
            v = fminf(fmaxf(v, -12.0f), 12.0f);          // clamped fast tanh
            float ev = __expf(-2.0f*v);
            float n = (1.0f - ev)/(1.0f + ev);
            float hnew = (1.0f - z)*n + z*hprev;
            float d = hnew - fv;
            lsum = fmaf(d, d, lsum);
            float nb = __shfl_down(hnew, 1);             // neighbor j+1, same wave
            if (!(j & 1)) {
                half2_t p; p[0] = (_Float16)hnew; p[1] = (_Float16)nb;
                ((unsigned int*)&hpk[cur ^ 1][0])[j >> 1] = __builtin_bit_cast(unsigned int, p);
            }
            hprev = hnew;
        }
        __syncthreads();   // protects hpk[cur^1] reads and part[] overwrite next step
        cur ^= 1;
    }
    if (tid < 256) red[j] = lsum;
    __syncthreads();
    for (int off = 128; off > 0; off >>= 1) {
        if (tid < off) red[tid] += red[tid + off];
        __syncthreads();
    }
    if (tid == 0) atomicAdd(ctx_acc, red[0]);
}

// Three occupancy shells for the 1024-thread body; runtime picks by reported numRegs/spill.
__global__ __launch_bounds__(1024, 1)
void gru_w1(const float* __restrict__ XP, const float* __restrict__ WHH,
            const float* __restrict__ bhh, const float* __restrict__ F,
            float* __restrict__ ctx_acc)
{ gru_body_1024(XP, WHH, bhh, F, ctx_acc); }

__global__ __launch_bounds__(1024, 4)
void gru_w2(const float* __restrict__ XP, const float* __restrict__ WHH,
            const float* __restrict__ bhh, const float* __restrict__ F,
            float* __restrict__ ctx_acc)
{ gru_body_1024(XP, WHH, bhh, F, ctx_acc); }

__global__ __attribute__((amdgpu_flat_work_group_size(1024, 1024), amdgpu_waves_per_eu(4, 4)))
void gru_w3(const float* __restrict__ XP, const float* __restrict__ WHH,
            const float* __restrict__ bhh, const float* __restrict__ F,
            float* __restrict__ ctx_acc)
{ gru_body_1024(XP, WHH, bhh, F, ctx_acc); }

// ---------------- 512-thread fallback (R3 behavior: 128 VGPR + spill replay, ~655 us) --------
__global__ __launch_bounds__(512)
void gru_c(const float* __restrict__ XP, const float* __restrict__ WHH,
           const float* __restrict__ bhh, const float* __restrict__ F,
           float* __restrict__ ctx_acc)
{
    __shared__ float part[3][2][256];
    __shared__ uint4 hpk[2][32];
    __shared__ float red[256];
    const int tid = threadIdx.x;
    const int b = blockIdx.x;
    const int j = tid & 255;
    const int q = tid >> 8;           // 0..1
    half2_t wr[64], wz[64], wn[64];
    {
        const float* rp = WHH + (size_t)j*256 + q*128;
        #pragma unroll
        for (int k = 0; k < 32; k++) {
            float4 vr = *(const float4*)(rp + 4*k);
            float4 vz = *(const float4*)(rp + 65536 + 4*k);
            float4 vn = *(const float4*)(rp + 131072 + 4*k);
            wr[2*k+0] = (half2_t){(_Float16)vr.x, (_Float16)vr.y};
            wr[2*k+1] = (half2_t){(_Float16)vr.z, (_Float16)vr.w};
            wz[2*k+0] = (half2_t){(_Float16)vz.x, (_Float16)vz.y};
            wz[2*k+1] = (half2_t){(_Float16)vz.z, (_Float16)vz.w};
            wn[2*k+0] = (half2_t){(_Float16)vn.x, (_Float16)vn.y};
            wn[2*k+1] = (half2_t){(_Float16)vn.z, (_Float16)vn.w};
        }
    }
    if (tid < 64) hpk[tid >> 5][tid & 31] = make_uint4(0u, 0u, 0u, 0u);
    const float bb0 = bhh[j], bb1 = bhh[256+j], bb2 = bhh[512+j];
    const float* xpb = XP + (size_t)b*NT*768;
    const float* fb  = F  + (size_t)b*NT*NDCB;
    float hprev = 0.0f, lsum = 0.0f;
    __syncthreads();
    int cur = 0;
    for (int t = 0; t < NT-1; t++) {
        float xr = 0.f, xz = 0.f, xn = 0.f, fv = 0.f;
        if (tid < 256) {
            const float* xp = xpb + (size_t)t*768;
            xr = xp[j]; xz = xp[256+j]; xn = xp[512+j];
            fv = fb[(size_t)(t+1)*NDCB + j];
        }
        float a0=0.f, c0=0.f, a1=0.f, c1=0.f, a2=0.f, c2=0.f;
        #pragma unroll
        for (int kk = 0; kk < 16; kk++) {
            uint4 hp = hpk[cur][q*16 + kk];
            half2_t h0 = __builtin_bit_cast(half2_t, hp.x);
            half2_t h1 = __builtin_bit_cast(half2_t, hp.y);
            half2_t h2 = __builtin_bit_cast(half2_t, hp.z);
            half2_t h3 = __builtin_bit_cast(half2_t, hp.w);
            a0 = dot2f(wr[4*kk+0], h0, a0); c0 = dot2f(wr[4*kk+1], h1, c0);
            a1 = dot2f(wz[4*kk+0], h0, a1); c1 = dot2f(wz[4*kk+1], h1, c1);
            a2 = dot2f(wn[4*kk+0], h0, a2); c2 = dot2f(wn[4*kk+1], h1, c2);
            a0 = dot2f(wr[4*kk+2], h2, a0); c0 = dot2f(wr[4*kk+3], h3, c0);
            a1 = dot2f(wz[4*kk+2], h2, a1); c1 = dot2f(wz[4*kk+3], h3, c1);
            a2 = dot2f(wn[4*kk+2], h2, a2); c2 = dot2f(wn[4*kk+3], h3, c2);
        }
        part[0][q][j] = a0 + c0; part[1][q][j] = a1 + c1; part[2][q][j] = a2 + c2;
        __syncthreads();
        if (tid < 256) {
            float ghr = part[0][0][j] + part[0][1][j] + bb0;
            float ghz = part[1][0][j] + part[1][1][j] + bb1;
            float ghn = part[2][0][j] + part[2][1][j] + bb2;
            float r = 1.0f/(1.0f + __expf(-(xr + ghr)));
            float z = 1.0f/(1.0f + __expf(-(xz + ghz)));
            float v = fmaf(r, ghn, xn);
            v = fminf(fmaxf(v, -12.0f), 12.0f);
            float ev = __expf(-2.0f*v);
            float n = (1.0f - ev)/(1.0f + ev);
            float hnew = (1.0f - z)*n + z*hprev;
            float d = hnew - fv;
            lsum = fmaf(d, d, lsum);
            float nb = __shfl_down(hnew, 1);
            if (!(j & 1)) {
                half2_t p; p[0] = (_Float16)hnew; p[1] = (_Float16)nb;
                ((unsigned int*)&hpk[cur ^ 1][0])[j >> 1] = __builtin_bit_cast(unsigned int, p);
            }
            hprev = hnew;
        }
        __syncthreads();
        cur ^= 1;
    }
    if (tid < 256) red[j] = lsum;
    __syncthreads();
    for (int off = 128; off > 0; off >>= 1) {
        if (tid < off) red[tid] += red[tid + off];
        __syncthreads();
    }
    if (tid == 0) atomicAdd(ctx_acc, red[0]);
}

// ---------------- small prep kernels ----------------
__global__ __launch_bounds__(256) void prep_kernel(
    const float* __restrict__ conv_w, float* __restrict__ w3,
    const float* __restrict__ wih, unsigned short* __restrict__ wihh,
    float* __restrict__ accv)
{
    int e = blockIdx.x*256 + threadIdx.x;     // < 196608
    if (e == 0) { accv[0] = 0.0f; accv[1] = 0.0f; }
    {   // w3[k][c][i] = conv_w[c][i][k]
        int k = e >> 16;
        int r = e & 65535;
        int c = r >> 8, i = r & 255;
        w3[e] = conv_w[(size_t)c*768 + i*3 + k];
    }
    {   // wih f32 -> f16 bits (768*256 = 196608 elements, exactly this grid)
        _Float16 h = (_Float16)wih[e];
        wihh[e] = __builtin_bit_cast(unsigned short, h);
    }
}

// codebook fp32 -> bf16 (RNE), for the MFMA prefilter
__global__ __launch_bounds__(256) void cb2bf_kernel(
    const float* __restrict__ cb, unsigned short* __restrict__ cbh)
{
    int e = (blockIdx.x*256 + threadIdx.x) * 4;   // 2,097,152 elems / 4
    float4 v = *(const float4*)&cb[e];
    unsigned short p0 = f2bf(v.x), p1 = f2bf(v.y), p2 = f2bf(v.z), p3 = f2bf(v.w);
    unsigned long long pk = (unsigned long long)p0 | ((unsigned long long)p1 << 16)
                          | ((unsigned long long)p2 << 32) | ((unsigned long long)p3 << 48);
    *(unsigned long long*)&cbh[e] = pk;
}

// s_c = fl32(exact sum c^2) via fp64   [LOCKED numerics]
__global__ __launch_bounds__(64) void cnorm_kernel(
    const float* __restrict__ CB, float* __restrict__ cn)
{
    const int k = blockIdx.x;
    const int lane = threadIdx.x;
    float4 v = *(const float4*)&CB[(size_t)k*NDCB + lane*4];
    double s = (double)v.x*(double)v.x + (double)v.y*(double)v.y
             + (double)v.z*(double)v.z + (double)v.w*(double)v.w;
    #pragma unroll
    for (int off = 32; off > 0; off >>= 1) s += __shfl_down(s, off);
    if (lane == 0) cn[k] = (float)s;
}

__global__ void finalize_kernel(const float* __restrict__ acc, float* __restrict__ out)
{
    if (threadIdx.x == 0) {
        float msd = acc[0] * (1.0f/4194304.0f);   // mean over 32*512*256
        float ctx = acc[1] * (1.0f/4184064.0f);   // mean over 32*511*256
        out[0] = msd;                 // commitment_loss
        out[1] = msd;                 // codebook_loss (same forward value)
        out[2] = ctx;                 // context_loss
        out[3] = 1.25f*msd + 0.1f*ctx; // vq_loss
    }
}

extern "C" void kernel_launch(void* const* d_in, const int* in_sizes, int n_in,
                              void* d_out, int out_size, void* d_ws, size_t ws_size,
                              hipStream_t stream) {
    const float* x      = (const float*)d_in[0];
    const float* w1     = (const float*)d_in[1];
    const float* b1     = (const float*)d_in[2];
    const float* w2     = (const float*)d_in[3];
    const float* b2     = (const float*)d_in[4];
    const float* conv_w = (const float*)d_in[5];
    const float* conv_b = (const float*)d_in[6];
    const float* cb     = (const float*)d_in[7];
    const float* wih    = (const float*)d_in[8];
    const float* whh    = (const float*)d_in[9];
    const float* bih    = (const float*)d_in[10];
    const float* bhh    = (const float*)d_in[11];
    float* out = (float*)d_out;

    // workspace layout (regions re-used once dead):
    //   [0,        16.7M)  feat  (fp32)          conv -> gru
    //   [16.7M,    50.3M)  h1    (fp32)          gemm1 -> gemm2
    //   [16.7M,    67.1M)  xproj (fp32, 50.3MB)  gemm3 -> gru   (overlays dead h1+h2)
    //   [50.3M,    67.1M)  h2    (fp32)          gemm2 -> conv
    //   [50.3M,    54.5M)  cbh   (bf16, 4MB)     cb2bf -> vq    (overlays dead h2)
    //   [67.1M, ...]       cn / w3 / wihh / accv
    char* ws = (char*)d_ws;
    float*  feat   = (float*)(ws + 0);
    float*  h1     = (float*)(ws + 16777216);
    float*  xproj  = (float*)(ws + 16777216);
    float*  h2     = (float*)(ws + 50331648);
    unsigned short* cbh = (unsigned short*)(ws + 50331648);
    float*  cn     = (float*)(ws + 67108864);
    float*  w3     = (float*)(ws + 67141632);
    unsigned short* wihh = (unsigned short*)(ws + 67928064);   // 393216 B (old wht slot)
    float*  accv   = (float*)(ws + 68714496);

    float* idx_out = out;                   // 16384 indices (as float)
    float* qout    = out + 16384;           // 4,194,304 quantized
    float* louts   = out + 16384 + 4194304; // 4 scalars

    // Pick the best 1024-thread GRU shell (pure host-side query; cached; capture-safe).
    // Weights resident needs numRegs >= ~116; prefer zero spill, accept <=64 B (few
    // rematerializable regs).  Fallback: known-good 512-thread gru_c (~655 us).
    static int gsel = -1;
    if (gsel < 0) {
        const void* cands[3] = {
            reinterpret_cast<const void*>(gru_w1),
            reinterpret_cast<const void*>(gru_w2),
            reinterpret_cast<const void*>(gru_w3) };
        gsel = 3;
        for (int pass = 0; pass < 2 && gsel == 3; ++pass) {
            size_t lim = (pass == 0) ? 0 : 64;
            for (int i = 0; i < 3 && gsel == 3; ++i) {
                hipFuncAttributes fa;
                if (hipFuncGetAttributes(&fa, cands[i]) == hipSuccess
                    && fa.localSizeBytes <= lim && fa.numRegs >= 116) gsel = i;
            }
        }
    }

    prep_kernel<<<768, 256, 0, stream>>>(conv_w, w3, wih, wihh, accv);
    cnorm_kernel<<<NKCB, 64, 0, stream>>>(cb, cn);
    gemm_nt_f64_kernel<true ><<<dim3(NHMID/64, NROWS/64), 256, 0, stream>>>(x,  w1, b1, h1, NROWS, NHMID, NDIN);
    gemm_nt_f64_kernel<true ><<<dim3(NDCB/64,  NROWS/64), 256, 0, stream>>>(h1, w2, b2, h2, NROWS, NDCB, NHMID);
    conv3_f64_kernel<<<dim3(NDCB/64, NROWS/64), 256, 0, stream>>>(h2, w3, conv_b, feat);
    cb2bf_kernel<<<2048, 256, 0, stream>>>(cb, cbh);   // after conv3: overlays dead h2
    vq_kernel<<<NROWS/64, 512, 0, stream>>>(feat, cb, cbh, cn, idx_out, qout, accv);
    xproj_mfma_kernel<<<NROWS/64, 512, 0, stream>>>(qout, wihh, bih, xproj);
    if (gsel == 0)      gru_w1<<<NB, 1024, 0, stream>>>(xproj, whh, bhh, feat, accv + 1);
    else if (gsel == 1) gru_w2<<<NB, 1024, 0, stream>>>(xproj, whh, bhh, feat, accv + 1);
    else if (gsel == 2) gru_w3<<<NB, 1024, 0, stream>>>(xproj, whh, bhh, feat, accv + 1);
    else                gru_c<<<NB, 512, 0, stream>>>(xproj, whh, bhh, feat, accv + 1);
    finalize_kernel<<<1, 64, 0, stream>>>(accv, louts);
}